// Round 7
// baseline (683.551 us; speedup 1.0000x reference)
//
#include <hip/hip_runtime.h>

#define KCODES 1024
#define DDIM 128
#define HW 64
#define NPIX (32 * HW * HW)         // 131072 pixels
#define PLANE (HW * HW)             // 4096
#define BSTRIDE (DDIM * PLANE)      // 524288 floats per batch image
#define CAP_A 65536
#define CAP_B 8192
// phase1 computes 1024*(Bsum_k - 2 z.c) with single fp16 MFMA (codebook
// pre-scaled by exactly 1024 so all values are fp16-normal; pow2 scale is
// error-free). Per-code error RMS ~0.015 scaled; MARGIN_SC = 0.4096 ~ 19
// sigma (+ covers ref fp32 band 3.2e-5*1024=0.033). Flagged pixels:
// 2 candidates -> exact fp64 2-way resolve; >=3 candidates -> full scan.
// phase1/3a/3b produce INDICES only; expand_kernel materializes out with
// full-cache-line stores (lane=w -> 256B contiguous per instruction).
#define MARGIN_SC 0.4096f
#define BAND 1e-4f                  // phase3b fp32-prefilter band (unscaled)

typedef __attribute__((ext_vector_type(8)))  _Float16 f16x8;  // MFMA A/B frag
typedef __attribute__((ext_vector_type(4)))  float    f32x4;
typedef __attribute__((ext_vector_type(16))) float    f32x16; // 32x32 C/D

// async global->LDS, 16B per lane (wave-uniform LDS base; HW adds lane*16)
__device__ inline void gll16(const void* g, void* l) {
    __builtin_amdgcn_global_load_lds(
        (const __attribute__((address_space(1))) unsigned int*)g,
        (__attribute__((address_space(3))) unsigned int*)l, 16, 0, 0);
}

// ---------------------------------------------------------------------------
// prep: blocks 0..3  -> Bsum[k] (numpy-pairwise, contract off) + 1024*Bsum
//       blocks 4..67 -> codebook*1024 as fp16 in 32x32x16 MFMA B-frag order
// frag layout: half off = ((c*8+s)*64 + l)*8 + j   (c=tile of 32 codes,
// s=kchunk of 16; lane l holds B[k=s*16+(l>>5)*8+j][n=c*32+(l&31)]).
// block 0 thread 0 also zeroes cntA/cntB (prep completes before phase1).
// ---------------------------------------------------------------------------
__global__ __launch_bounds__(256) void prep_kernel(const float* __restrict__ cb,
                                                   float* __restrict__ Bsum,
                                                   float* __restrict__ Bs1024,
                                                   _Float16* __restrict__ bs16,
                                                   int* __restrict__ cnts) {
    int bid = blockIdx.x;
    if (bid < 4) {
        if (bid == 0 && threadIdx.x == 0) { cnts[0] = 0; cnts[1] = 0; }
        {
#pragma clang fp contract(off)
            int k = bid * 256 + threadIdx.x;
            const float* row = cb + k * DDIM;
            float r0,r1,r2,r3,r4,r5,r6,r7;
            r0 = row[0]*row[0]; r1 = row[1]*row[1]; r2 = row[2]*row[2]; r3 = row[3]*row[3];
            r4 = row[4]*row[4]; r5 = row[5]*row[5]; r6 = row[6]*row[6]; r7 = row[7]*row[7];
#pragma unroll
            for (int i = 8; i < DDIM; i += 8) {
                r0 += row[i+0]*row[i+0]; r1 += row[i+1]*row[i+1];
                r2 += row[i+2]*row[i+2]; r3 += row[i+3]*row[i+3];
                r4 += row[i+4]*row[i+4]; r5 += row[i+5]*row[i+5];
                r6 += row[i+6]*row[i+6]; r7 += row[i+7]*row[i+7];
            }
            float bs = ((r0+r1)+(r2+r3)) + ((r4+r5)+(r6+r7));
            Bsum[k] = bs;
            Bs1024[k] = 1024.0f * bs;          // pow2 scale: exact
        }
    } else {
        int t = (bid - 4) * 256 + threadIdx.x; // 16384 = 32c * 8s * 64l
        int c = t >> 9, s = (t >> 6) & 7, l = t & 63;
        int n = l & 31, half = l >> 5;
        int code = c * 32 + n;
        int d0 = s * 16 + half * 8;
        const float* row = cb + code * DDIM + d0;
        f32x4 f0 = *(const f32x4*)(row);
        f32x4 f1 = *(const f32x4*)(row + 4);
        f16x8 v;
#pragma unroll
        for (int e = 0; e < 4; ++e) {
            v[e]     = (_Float16)(1024.0f * f0[e]);   // RNE cvt
            v[4 + e] = (_Float16)(1024.0f * f1[e]);
        }
        *(f16x8*)(bs16 + ((size_t)((c * 8 + s) * 64 + l)) * 8) = v;
    }
}

// ---------------------------------------------------------------------------
// phase1: single-fp16 32x32x16 MFMA distance (scaled by 1024) + top-3 argmin.
// Block = 4 waves = 128 px; each wave owns 32 contiguous w of one h row.
// B: one 8KB c-tile per LDS buffer, double-buffered, staged with
// global_load_lds dwordx4 (2 per wave); one barrier per c-tile (32 total,
// R2-proven cadence). acc init = 1024*Bsum[k] (global, L2-resident).
// OUTPUT: indices only (idx[pix]) -- no scattered f32 stores, no cb gather.
// Tracks (m1,i1,m2,i2,m3): m2-m1<=MARGIN -> listA{pix,k1,k2};
// additionally m3-m1<=MARGIN -> listB{pix} (full-scan fallback, rare).
// C/D: col(code)=lane&31, row(pixel)=(r&3)+8*(r>>2)+4*(lane>>5).
// ---------------------------------------------------------------------------
__global__ __launch_bounds__(256, 4) void phase1_mfma(
    const float* __restrict__ z, const _Float16* __restrict__ bs16,
    const float* __restrict__ Bs1024, int* __restrict__ idx,
    int* __restrict__ cntA, int2* __restrict__ listA,
    int* __restrict__ cntB, int* __restrict__ listB)
{
    __shared__ __align__(16) _Float16 btile[2][4096];   // 2 x 8KB
    __shared__ int idxb[128];
    const int tid = threadIdx.x;
    const int lane = tid & 63, wv = tid >> 6;
    const int wg = blockIdx.x;                 // 1024 blocks
    const int b = wg >> 5;
    const int h = (wg & 31) * 2 + (wv >> 1);
    const int w0 = (wv & 1) * 32;
    const int col = lane & 31, half = lane >> 5;

    // A fragments: pixel m=col -> w=w0+col; chunk s covers d=s*16+half*8+e
    const float* zbase = z + (size_t)b * BSTRIDE + h * HW + w0 + col;
    f16x8 za[8];
#pragma unroll
    for (int s = 0; s < 8; ++s) {
        const float* zp = zbase + (size_t)(s * 16 + half * 8) * PLANE;
        f16x8 a;
#pragma unroll
        for (int e = 0; e < 8; ++e)
            a[e] = (_Float16)(-2.0f * zp[(size_t)e * PLANE]);
        za[s] = a;
    }

    float m1[16], m2[16], m3[16]; int i1[16], i2[16];
#pragma unroll
    for (int r = 0; r < 16; ++r) {
        m1[r] = 3.4e38f; m2[r] = 3.4e38f; m3[r] = 3.4e38f; i1[r] = 0; i2[r] = 0;
    }

    // staging: wave wv owns bytes [wv*2048, +2048) of each 8KB buffer
    const char* bb = (const char*)bs16;
#define STAGE(BUF, C) do {                                                   \
        const char* s_ = bb + (size_t)(C) * 8192 + wv * 2048 + lane * 16;    \
        char* d_ = (char*)&btile[BUF][0] + wv * 2048;                        \
        gll16(s_,        d_);                                                \
        gll16(s_ + 1024, d_ + 1024);                                         \
    } while (0)

    STAGE(0, 0);
    __syncthreads();

    for (int c = 0; c < 32; ++c) {
        const int cur = c & 1;
        if (c < 31) STAGE(cur ^ 1, c + 1);     // prefetch next 8KB
        const f16x8* bf = (const f16x8*)btile[cur];
        int kcol = c * 32 + col;
        float bsv = Bs1024[kcol];              // scalar per-lane, L2-resident
        f32x16 acc;
#pragma unroll
        for (int r = 0; r < 16; ++r) acc[r] = bsv;
#pragma unroll
        for (int s = 0; s < 8; ++s) {
            f16x8 bh = bf[s * 64 + lane];
            acc = __builtin_amdgcn_mfma_f32_32x32x16_f16(za[s], bh, acc, 0, 0, 0);
        }
        // top-3 values + top-2 indices (9 VALU/row)
#pragma unroll
        for (int r = 0; r < 16; ++r) {
            float dv = acc[r];
            bool lt1 = dv < m1[r];
            bool lt2 = dv < m2[r];
            m3[r] = lt2 ? m2[r] : fminf(m3[r], dv);
            m2[r] = lt1 ? m1[r] : (lt2 ? dv : m2[r]);
            i2[r] = lt1 ? i1[r] : (lt2 ? kcol : i2[r]);
            m1[r] = lt1 ? dv : m1[r];
            i1[r] = lt1 ? kcol : i1[r];
        }
        __syncthreads();                       // reads done + prefetch landed
    }
#undef STAGE

    // merge sorted-3 tuples across the 32 lanes (code columns) per row set
#pragma unroll
    for (int mask = 1; mask <= 16; mask <<= 1) {
#pragma unroll
        for (int r = 0; r < 16; ++r) {
            float b1 = __shfl_xor(m1[r], mask, 64);
            float b2 = __shfl_xor(m2[r], mask, 64);
            float b3 = __shfl_xor(m3[r], mask, 64);
            int  ib1 = __shfl_xor(i1[r], mask, 64);
            int  ib2 = __shfl_xor(i2[r], mask, 64);
            float a1 = m1[r], a2 = m2[r], a3 = m3[r];
            int  ia1 = i1[r], ia2 = i2[r];
            bool bfi = (b1 < a1) || (b1 == a1 && ib1 < ia1);
            float x1 = bfi ? b1 : a1;  int xi1 = bfi ? ib1 : ia1;
            float x2 = bfi ? b2 : a2;  int xi2 = bfi ? ib2 : ia2;
            float x3 = bfi ? b3 : a3;
            float y1 = bfi ? a1 : b1;  int yi1 = bfi ? ia1 : ib1;
            float y2 = bfi ? a2 : b2;
            bool ys = (y1 < x2) || (y1 == x2 && yi1 < xi2);
            m1[r] = x1; i1[r] = xi1;
            m2[r] = ys ? y1 : x2;  i2[r] = ys ? yi1 : xi2;
            m3[r] = ys ? fminf(x2, y2) : fminf(x3, y1);
        }
    }

    if (col == 0) {                  // 2 writer lanes per wave (half=0/1)
#pragma unroll
        for (int r = 0; r < 16; ++r) {
            int row = (r & 3) + 8 * (r >> 2) + 4 * half;
            idxb[wv * 32 + row] = i1[r];
            if (m2[r] - m1[r] <= MARGIN_SC) {           // ambiguous
                int pix = wg * 128 + wv * 32 + row;
                int pos = atomicAdd(cntA, 1);
                if (pos < CAP_A) {
                    int2 rec; rec.x = pix; rec.y = i1[r] | (i2[r] << 16);
                    listA[pos] = rec;
                }
                if (m3[r] - m1[r] <= MARGIN_SC) {       // >=3 cands (rare)
                    int pb = atomicAdd(cntB, 1);
                    if (pb < CAP_B) listB[pb] = pix;
                }
            }
        }
    }
    __syncthreads();

    if (tid < 128) idx[wg * 128 + tid] = idxb[tid];     // coalesced dump
}

// ---------------------------------------------------------------------------
// phase3a: resolve 2-candidate ambiguous pixels -> fix idx[pix]. One wave
// per item.  A = numpy-pairwise sum of z^2 (fp32, contract off); p = fp64
// dot (lane-split + shuffle reduce); D_k = fl32(fl32(A+Bsum_k) - fl32(2p));
// winner = lex min (D, k). No __syncthreads in item loop (waves diverge).
// ---------------------------------------------------------------------------
__global__ __launch_bounds__(256, 4) void phase3a_kernel(
    const float* __restrict__ z, const float* __restrict__ cb,
    const float* __restrict__ Bsum, int* __restrict__ idx,
    const int* __restrict__ cntA, const int2* __restrict__ listA)
{
    __shared__ float zsh[4][128];
    const int tid = threadIdx.x, lane = tid & 63, wv = tid >> 6;
    int gwave = (blockIdx.x * 256 + tid) >> 6;
    int nwaves = gridDim.x * 4;
    int nitems = *cntA; if (nitems > CAP_A) nitems = CAP_A;

    for (int item = gwave; item < nitems; item += nwaves) {
        int2 rec = listA[item];
        int pix = rec.x;
        int k1 = rec.y & 0xFFFF, k2 = rec.y >> 16;
        int b = pix >> 12, h = (pix >> 6) & 63, w = pix & 63;
        const float* zp = z + (size_t)b * BSTRIDE + h * HW + w;

        float za = zp[(size_t)lane * PLANE];
        float zb = zp[(size_t)(lane + 64) * PLANE];
        zsh[wv][lane] = za;
        zsh[wv][lane + 64] = zb;

        float Apair;
        {
#pragma clang fp contract(off)
            const float* zr = zsh[wv];
            float r0,r1,r2,r3,r4,r5,r6,r7;
            r0 = zr[0]*zr[0]; r1 = zr[1]*zr[1]; r2 = zr[2]*zr[2]; r3 = zr[3]*zr[3];
            r4 = zr[4]*zr[4]; r5 = zr[5]*zr[5]; r6 = zr[6]*zr[6]; r7 = zr[7]*zr[7];
#pragma unroll
            for (int i = 8; i < DDIM; i += 8) {
                r0 += zr[i+0]*zr[i+0]; r1 += zr[i+1]*zr[i+1];
                r2 += zr[i+2]*zr[i+2]; r3 += zr[i+3]*zr[i+3];
                r4 += zr[i+4]*zr[i+4]; r5 += zr[i+5]*zr[i+5];
                r6 += zr[i+6]*zr[i+6]; r7 += zr[i+7]*zr[i+7];
            }
            Apair = ((r0+r1)+(r2+r3)) + ((r4+r5)+(r6+r7));
        }

        const float* c1 = cb + (size_t)k1 * DDIM;
        const float* c2 = cb + (size_t)k2 * DDIM;
        double p1 = fma((double)za, (double)c1[lane],
                        (double)zb * (double)c1[lane + 64]);
        double p2 = fma((double)za, (double)c2[lane],
                        (double)zb * (double)c2[lane + 64]);
        for (int off = 32; off; off >>= 1) {
            p1 += __shfl_xor(p1, off, 64);
            p2 += __shfl_xor(p2, off, 64);
        }
        float u1 = (float)(2.0 * p1), u2 = (float)(2.0 * p2);
        float D1, D2;
        {
#pragma clang fp contract(off)
            float t1 = Apair + Bsum[k1];
            float t2 = Apair + Bsum[k2];
            D1 = t1 - u1; D2 = t2 - u2;
        }
        int wk = (D1 < D2 || (D1 == D2 && k1 < k2)) ? k1 : k2;
        if (lane == 0) idx[pix] = wk;
    }
}

// ---------------------------------------------------------------------------
// phase3b: exact full-scan resolve for >=3-candidate pixels (rare) -> fix
// idx[pix]. One wave per item; fp32 prefilter over all 1024 codes (16/lane),
// candidates within smin+BAND get the exact fp64 path. Runs after phase3a
// so its idx writes win.
// ---------------------------------------------------------------------------
__global__ __launch_bounds__(256, 4) void phase3b_kernel(
    const float* __restrict__ z, const float* __restrict__ cb,
    const float* __restrict__ Bsum, int* __restrict__ idx,
    const int* __restrict__ cntB, const int* __restrict__ listB)
{
    __shared__ float zsh[4][128];
    const int tid = threadIdx.x, lane = tid & 63, wv = tid >> 6;
    int gwave = (blockIdx.x * 256 + tid) >> 6;
    int nwaves = gridDim.x * 4;
    int nitems = *cntB; if (nitems > CAP_B) nitems = CAP_B;

    for (int item = gwave; item < nitems; item += nwaves) {
        int pix = listB[item];
        int b = pix >> 12, h = (pix >> 6) & 63, w = pix & 63;
        const float* zp = z + (size_t)b * BSTRIDE + h * HW + w;

        float za = zp[(size_t)lane * PLANE];
        float zb = zp[(size_t)(lane + 64) * PLANE];
        zsh[wv][lane] = za;                    // wave-internal: in-order LDS
        zsh[wv][lane + 64] = zb;
        const float* zr = zsh[wv];

        float Apair;
        {
#pragma clang fp contract(off)
            float r0,r1,r2,r3,r4,r5,r6,r7;
            r0 = zr[0]*zr[0]; r1 = zr[1]*zr[1]; r2 = zr[2]*zr[2]; r3 = zr[3]*zr[3];
            r4 = zr[4]*zr[4]; r5 = zr[5]*zr[5]; r6 = zr[6]*zr[6]; r7 = zr[7]*zr[7];
#pragma unroll
            for (int i = 8; i < DDIM; i += 8) {
                r0 += zr[i+0]*zr[i+0]; r1 += zr[i+1]*zr[i+1];
                r2 += zr[i+2]*zr[i+2]; r3 += zr[i+3]*zr[i+3];
                r4 += zr[i+4]*zr[i+4]; r5 += zr[i+5]*zr[i+5];
                r6 += zr[i+6]*zr[i+6]; r7 += zr[i+7]*zr[i+7];
            }
            Apair = ((r0+r1)+(r2+r3)) + ((r4+r5)+(r6+r7));
        }

        // fp32 prefilter: lane owns codes k = g*64+lane, g=0..15
        float dot[16];
#pragma unroll
        for (int g = 0; g < 16; ++g) dot[g] = 0.0f;
        for (int i = 0; i < 32; ++i) {
            f32x4 zv = *(const f32x4*)(zr + i * 4);   // broadcast LDS read
#pragma unroll
            for (int g = 0; g < 16; ++g) {
                const f32x4 cv = *(const f32x4*)(cb + (size_t)(g * 64 + lane) * DDIM + i * 4);
                dot[g] = __builtin_fmaf(zv[0], cv[0],
                         __builtin_fmaf(zv[1], cv[1],
                         __builtin_fmaf(zv[2], cv[2],
                         __builtin_fmaf(zv[3], cv[3], dot[g]))));
            }
        }
        float est[16]; float smin = 3.4e38f;
#pragma unroll
        for (int g = 0; g < 16; ++g) {
            est[g] = Bsum[g * 64 + lane] - 2.0f * dot[g];
            smin = fminf(smin, est[g]);
        }
        for (int off = 32; off; off >>= 1)
            smin = fminf(smin, __shfl_xor(smin, off, 64));

        float bd = 3.4e38f; int bk = 1 << 30;
#pragma unroll 1
        for (int g = 0; g < 16; ++g) {
            if (est[g] <= smin + BAND) {
                int k = g * 64 + lane;
                const float* c = cb + (size_t)k * DDIM;
                double p = 0.0;
                for (int i = 0; i < DDIM; ++i)
                    p = fma((double)zr[i], (double)c[i], p);
                float Dk;
                {
#pragma clang fp contract(off)
                    float t1 = Apair + Bsum[k];
                    float u = (float)(2.0 * p);
                    Dk = t1 - u;
                }
                if (Dk < bd || (Dk == bd && k < bk)) { bd = Dk; bk = k; }
            }
        }
        for (int off = 32; off; off >>= 1) {
            float od = __shfl_xor(bd, off, 64);
            int   ok = __shfl_xor(bk, off, 64);
            bool better = (od < bd) || (od == bd && ok < bk);
            bd = better ? od : bd;
            bk = better ? ok : bk;
        }
        if (lane == 0) idx[pix] = bk;
    }
}

// ---------------------------------------------------------------------------
// expand: out[b,:,h,w] = cb[idx[pix]]. Block = one (b,h) row; lane = w so
// every store instruction writes one full 256-B contiguous w-row (no RMW,
// no partial lines). cb gather per block touches <=32 KB -> L1-resident.
// ---------------------------------------------------------------------------
__global__ __launch_bounds__(256) void expand_kernel(
    const float* __restrict__ cb, const int* __restrict__ idx,
    float* __restrict__ out)
{
    const int blk = blockIdx.x;                // 2048 = b*64 + h
    const int b = blk >> 6, h = blk & 63;
    const int tid = threadIdx.x, w = tid & 63, wv = tid >> 6;
    const int id = idx[blk * 64 + w];          // same 64 ids per wave (L1)
    const float* crow = cb + (size_t)id * DDIM;
    float* ob = out + (size_t)b * BSTRIDE + h * HW + w;
#pragma unroll
    for (int d0 = 0; d0 < 32; d0 += 4) {
        int d = wv * 32 + d0;
        f32x4 v = *(const f32x4*)(crow + d);   // 16B gather per lane
        ob[(size_t)(d + 0) * PLANE] = v[0];
        ob[(size_t)(d + 1) * PLANE] = v[1];
        ob[(size_t)(d + 2) * PLANE] = v[2];
        ob[(size_t)(d + 3) * PLANE] = v[3];
    }
}

// ---------------------------------------------------------------------------
extern "C" void kernel_launch(void* const* d_in, const int* in_sizes, int n_in,
                              void* d_out, int out_size, void* d_ws, size_t ws_size,
                              hipStream_t stream) {
    const float* z  = (const float*)d_in[0];
    const float* cb = (const float*)d_in[1];
    float* out = (float*)d_out;

    // ws: Bsum 4K | Bs1024 4K | cnts 4K | bs16 256K | listA 512K | listB 32K
    //     | idx 512K
    float* Bsum   = (float*)d_ws;
    float* Bs1024 = (float*)((char*)d_ws + 4096);
    int*   cnts   = (int*)((char*)d_ws + 8192);
    _Float16* bs16 = (_Float16*)((char*)d_ws + 12288);
    int2*  listA  = (int2*)((char*)d_ws + 12288 + 262144);
    int*   listB  = (int*)((char*)d_ws + 12288 + 262144 + 524288);
    int*   idx    = (int*)((char*)d_ws + 12288 + 262144 + 524288 + 32768);
    int* cntA = cnts; int* cntB = cnts + 1;

    prep_kernel<<<68, 256, 0, stream>>>(cb, Bsum, Bs1024, bs16, cnts);
    phase1_mfma<<<NPIX / 128, 256, 0, stream>>>(z, bs16, Bs1024, idx,
                                                cntA, listA, cntB, listB);
    phase3a_kernel<<<1024, 256, 0, stream>>>(z, cb, Bsum, idx, cntA, listA);
    phase3b_kernel<<<128, 256, 0, stream>>>(z, cb, Bsum, idx, cntB, listB);
    expand_kernel<<<2048, 256, 0, stream>>>(cb, idx, out);
}

// Round 8
// 615.159 us; speedup vs baseline: 1.1112x; 1.1112x over previous
//
#include <hip/hip_runtime.h>

#define KCODES 1024
#define DDIM 128
#define HW 64
#define NPIX (32 * HW * HW)         // 131072 pixels
#define PLANE (HW * HW)             // 4096
#define BSTRIDE (DDIM * PLANE)      // 524288 floats per batch image
#define CAP_A 65536
#define CAP_B 8192
// phase1 computes 1024*(Bsum_k - 2 z.c) with single fp16 MFMA (codebook
// pre-scaled by exactly 1024 so all values are fp16-normal; pow2 scale is
// error-free). Per-code error RMS ~0.015 scaled; MARGIN_SC = 0.4096 ~ 19
// sigma (+ covers ref fp32 band 3.2e-5*1024=0.033). Flagged pixels:
// 2 candidates -> exact fp64 2-way resolve; >=3 candidates -> full scan.
// phase1/3a/3b produce INDICES only; expand_kernel materializes out with
// full-cache-line stores (lane=w -> 256B contiguous per instruction).
// NOTE: phase1 needs ~160-190 VGPRs live (tracking 80 + za 32 + acc 16 +
// addressing). launch_bounds min-waves MUST stay at 2: 3 caps VGPR at 84,
// 4 caps at 64 -> massive scratch spills (R6: 143MB, R7: 120MB WRITE).
#define MARGIN_SC 0.4096f
#define BAND 1e-4f                  // phase3b fp32-prefilter band (unscaled)

typedef __attribute__((ext_vector_type(8)))  _Float16 f16x8;  // MFMA A/B frag
typedef __attribute__((ext_vector_type(4)))  float    f32x4;
typedef __attribute__((ext_vector_type(16))) float    f32x16; // 32x32 C/D

// async global->LDS, 16B per lane (wave-uniform LDS base; HW adds lane*16)
__device__ inline void gll16(const void* g, void* l) {
    __builtin_amdgcn_global_load_lds(
        (const __attribute__((address_space(1))) unsigned int*)g,
        (__attribute__((address_space(3))) unsigned int*)l, 16, 0, 0);
}

// ---------------------------------------------------------------------------
// prep: blocks 0..3  -> Bsum[k] (numpy-pairwise, contract off) + 1024*Bsum
//       blocks 4..67 -> codebook*1024 as fp16 in 32x32x16 MFMA B-frag order
// frag layout: half off = ((c*8+s)*64 + l)*8 + j   (c=tile of 32 codes,
// s=kchunk of 16; lane l holds B[k=s*16+(l>>5)*8+j][n=c*32+(l&31)]).
// block 0 thread 0 also zeroes cntA/cntB (prep completes before phase1).
// ---------------------------------------------------------------------------
__global__ __launch_bounds__(256) void prep_kernel(const float* __restrict__ cb,
                                                   float* __restrict__ Bsum,
                                                   float* __restrict__ Bs1024,
                                                   _Float16* __restrict__ bs16,
                                                   int* __restrict__ cnts) {
    int bid = blockIdx.x;
    if (bid < 4) {
        if (bid == 0 && threadIdx.x == 0) { cnts[0] = 0; cnts[1] = 0; }
        {
#pragma clang fp contract(off)
            int k = bid * 256 + threadIdx.x;
            const float* row = cb + k * DDIM;
            float r0,r1,r2,r3,r4,r5,r6,r7;
            r0 = row[0]*row[0]; r1 = row[1]*row[1]; r2 = row[2]*row[2]; r3 = row[3]*row[3];
            r4 = row[4]*row[4]; r5 = row[5]*row[5]; r6 = row[6]*row[6]; r7 = row[7]*row[7];
#pragma unroll
            for (int i = 8; i < DDIM; i += 8) {
                r0 += row[i+0]*row[i+0]; r1 += row[i+1]*row[i+1];
                r2 += row[i+2]*row[i+2]; r3 += row[i+3]*row[i+3];
                r4 += row[i+4]*row[i+4]; r5 += row[i+5]*row[i+5];
                r6 += row[i+6]*row[i+6]; r7 += row[i+7]*row[i+7];
            }
            float bs = ((r0+r1)+(r2+r3)) + ((r4+r5)+(r6+r7));
            Bsum[k] = bs;
            Bs1024[k] = 1024.0f * bs;          // pow2 scale: exact
        }
    } else {
        int t = (bid - 4) * 256 + threadIdx.x; // 16384 = 32c * 8s * 64l
        int c = t >> 9, s = (t >> 6) & 7, l = t & 63;
        int n = l & 31, half = l >> 5;
        int code = c * 32 + n;
        int d0 = s * 16 + half * 8;
        const float* row = cb + code * DDIM + d0;
        f32x4 f0 = *(const f32x4*)(row);
        f32x4 f1 = *(const f32x4*)(row + 4);
        f16x8 v;
#pragma unroll
        for (int e = 0; e < 4; ++e) {
            v[e]     = (_Float16)(1024.0f * f0[e]);   // RNE cvt
            v[4 + e] = (_Float16)(1024.0f * f1[e]);
        }
        *(f16x8*)(bs16 + ((size_t)((c * 8 + s) * 64 + l)) * 8) = v;
    }
}

// ---------------------------------------------------------------------------
// phase1: single-fp16 32x32x16 MFMA distance (scaled by 1024) + top-3 argmin.
// Block = 4 waves = 128 px; each wave owns 32 contiguous w of one h row.
// B: one 8KB c-tile per LDS buffer, double-buffered, staged with
// global_load_lds dwordx4 (2 per wave); one barrier per c-tile.
// acc init = 1024*Bsum[k] (L1/L2-resident coalesced load).
// OUTPUT: indices only (idx[pix]) -- no scattered f32 stores, no cb gather.
// Tracks (m1,i1,m2,i2,m3): m2-m1<=MARGIN -> listA{pix,k1,k2};
// additionally m3-m1<=MARGIN -> listB{pix} (full-scan fallback, rare).
// C/D: col(code)=lane&31, row(pixel)=(r&3)+8*(r>>2)+4*(lane>>5).
// ---------------------------------------------------------------------------
__global__ __launch_bounds__(256, 2) void phase1_mfma(
    const float* __restrict__ z, const _Float16* __restrict__ bs16,
    const float* __restrict__ Bs1024, int* __restrict__ idx,
    int* __restrict__ cntA, int2* __restrict__ listA,
    int* __restrict__ cntB, int* __restrict__ listB)
{
    __shared__ __align__(16) _Float16 btile[2][4096];   // 2 x 8KB
    __shared__ int idxb[128];
    const int tid = threadIdx.x;
    const int lane = tid & 63, wv = tid >> 6;
    const int wg = blockIdx.x;                 // 1024 blocks
    const int b = wg >> 5;
    const int h = (wg & 31) * 2 + (wv >> 1);
    const int w0 = (wv & 1) * 32;
    const int col = lane & 31, half = lane >> 5;

    // A fragments: pixel m=col -> w=w0+col; chunk s covers d=s*16+half*8+e
    const float* zbase = z + (size_t)b * BSTRIDE + h * HW + w0 + col;
    f16x8 za[8];
#pragma unroll
    for (int s = 0; s < 8; ++s) {
        const float* zp = zbase + (size_t)(s * 16 + half * 8) * PLANE;
        f16x8 a;
#pragma unroll
        for (int e = 0; e < 8; ++e)
            a[e] = (_Float16)(-2.0f * zp[(size_t)e * PLANE]);
        za[s] = a;
    }

    float m1[16], m2[16], m3[16]; int i1[16], i2[16];
#pragma unroll
    for (int r = 0; r < 16; ++r) {
        m1[r] = 3.4e38f; m2[r] = 3.4e38f; m3[r] = 3.4e38f; i1[r] = 0; i2[r] = 0;
    }

    // staging: wave wv owns bytes [wv*2048, +2048) of each 8KB buffer
    const char* bb = (const char*)bs16;
#define STAGE(BUF, C) do {                                                   \
        const char* s_ = bb + (size_t)(C) * 8192 + wv * 2048 + lane * 16;    \
        char* d_ = (char*)&btile[BUF][0] + wv * 2048;                        \
        gll16(s_,        d_);                                                \
        gll16(s_ + 1024, d_ + 1024);                                         \
    } while (0)

    STAGE(0, 0);
    __syncthreads();

    for (int c = 0; c < 32; ++c) {
        const int cur = c & 1;
        if (c < 31) STAGE(cur ^ 1, c + 1);     // prefetch next 8KB
        const f16x8* bf = (const f16x8*)btile[cur];
        int kcol = c * 32 + col;
        float bsv = Bs1024[kcol];              // coalesced, L1-resident
        f32x16 acc;
#pragma unroll
        for (int r = 0; r < 16; ++r) acc[r] = bsv;
#pragma unroll
        for (int s = 0; s < 8; ++s) {
            f16x8 bh = bf[s * 64 + lane];
            acc = __builtin_amdgcn_mfma_f32_32x32x16_f16(za[s], bh, acc, 0, 0, 0);
        }
        // top-3 values + top-2 indices (9 VALU/row)
#pragma unroll
        for (int r = 0; r < 16; ++r) {
            float dv = acc[r];
            bool lt1 = dv < m1[r];
            bool lt2 = dv < m2[r];
            m3[r] = lt2 ? m2[r] : fminf(m3[r], dv);
            m2[r] = lt1 ? m1[r] : (lt2 ? dv : m2[r]);
            i2[r] = lt1 ? i1[r] : (lt2 ? kcol : i2[r]);
            m1[r] = lt1 ? dv : m1[r];
            i1[r] = lt1 ? kcol : i1[r];
        }
        __syncthreads();                       // reads done + prefetch landed
    }
#undef STAGE

    // merge sorted-3 tuples across the 32 lanes (code columns) per row set
#pragma unroll
    for (int mask = 1; mask <= 16; mask <<= 1) {
#pragma unroll
        for (int r = 0; r < 16; ++r) {
            float b1 = __shfl_xor(m1[r], mask, 64);
            float b2 = __shfl_xor(m2[r], mask, 64);
            float b3 = __shfl_xor(m3[r], mask, 64);
            int  ib1 = __shfl_xor(i1[r], mask, 64);
            int  ib2 = __shfl_xor(i2[r], mask, 64);
            float a1 = m1[r], a2 = m2[r], a3 = m3[r];
            int  ia1 = i1[r], ia2 = i2[r];
            bool bfi = (b1 < a1) || (b1 == a1 && ib1 < ia1);
            float x1 = bfi ? b1 : a1;  int xi1 = bfi ? ib1 : ia1;
            float x2 = bfi ? b2 : a2;  int xi2 = bfi ? ib2 : ia2;
            float x3 = bfi ? b3 : a3;
            float y1 = bfi ? a1 : b1;  int yi1 = bfi ? ia1 : ib1;
            float y2 = bfi ? a2 : b2;
            bool ys = (y1 < x2) || (y1 == x2 && yi1 < xi2);
            m1[r] = x1; i1[r] = xi1;
            m2[r] = ys ? y1 : x2;  i2[r] = ys ? yi1 : xi2;
            m3[r] = ys ? fminf(x2, y2) : fminf(x3, y1);
        }
    }

    if (col == 0) {                  // 2 writer lanes per wave (half=0/1)
#pragma unroll
        for (int r = 0; r < 16; ++r) {
            int row = (r & 3) + 8 * (r >> 2) + 4 * half;
            idxb[wv * 32 + row] = i1[r];
            if (m2[r] - m1[r] <= MARGIN_SC) {           // ambiguous
                int pix = wg * 128 + wv * 32 + row;
                int pos = atomicAdd(cntA, 1);
                if (pos < CAP_A) {
                    int2 rec; rec.x = pix; rec.y = i1[r] | (i2[r] << 16);
                    listA[pos] = rec;
                }
                if (m3[r] - m1[r] <= MARGIN_SC) {       // >=3 cands (rare)
                    int pb = atomicAdd(cntB, 1);
                    if (pb < CAP_B) listB[pb] = pix;
                }
            }
        }
    }
    __syncthreads();

    if (tid < 128) idx[wg * 128 + tid] = idxb[tid];     // coalesced dump
}

// ---------------------------------------------------------------------------
// phase3a: resolve 2-candidate ambiguous pixels -> fix idx[pix]. One wave
// per item.  A = numpy-pairwise sum of z^2 (fp32, contract off); p = fp64
// dot (lane-split + shuffle reduce); D_k = fl32(fl32(A+Bsum_k) - fl32(2p));
// winner = lex min (D, k). No __syncthreads in item loop (waves diverge).
// ---------------------------------------------------------------------------
__global__ __launch_bounds__(256, 4) void phase3a_kernel(
    const float* __restrict__ z, const float* __restrict__ cb,
    const float* __restrict__ Bsum, int* __restrict__ idx,
    const int* __restrict__ cntA, const int2* __restrict__ listA)
{
    __shared__ float zsh[4][128];
    const int tid = threadIdx.x, lane = tid & 63, wv = tid >> 6;
    int gwave = (blockIdx.x * 256 + tid) >> 6;
    int nwaves = gridDim.x * 4;
    int nitems = *cntA; if (nitems > CAP_A) nitems = CAP_A;

    for (int item = gwave; item < nitems; item += nwaves) {
        int2 rec = listA[item];
        int pix = rec.x;
        int k1 = rec.y & 0xFFFF, k2 = rec.y >> 16;
        int b = pix >> 12, h = (pix >> 6) & 63, w = pix & 63;
        const float* zp = z + (size_t)b * BSTRIDE + h * HW + w;

        float za = zp[(size_t)lane * PLANE];
        float zb = zp[(size_t)(lane + 64) * PLANE];
        zsh[wv][lane] = za;
        zsh[wv][lane + 64] = zb;

        float Apair;
        {
#pragma clang fp contract(off)
            const float* zr = zsh[wv];
            float r0,r1,r2,r3,r4,r5,r6,r7;
            r0 = zr[0]*zr[0]; r1 = zr[1]*zr[1]; r2 = zr[2]*zr[2]; r3 = zr[3]*zr[3];
            r4 = zr[4]*zr[4]; r5 = zr[5]*zr[5]; r6 = zr[6]*zr[6]; r7 = zr[7]*zr[7];
#pragma unroll
            for (int i = 8; i < DDIM; i += 8) {
                r0 += zr[i+0]*zr[i+0]; r1 += zr[i+1]*zr[i+1];
                r2 += zr[i+2]*zr[i+2]; r3 += zr[i+3]*zr[i+3];
                r4 += zr[i+4]*zr[i+4]; r5 += zr[i+5]*zr[i+5];
                r6 += zr[i+6]*zr[i+6]; r7 += zr[i+7]*zr[i+7];
            }
            Apair = ((r0+r1)+(r2+r3)) + ((r4+r5)+(r6+r7));
        }

        const float* c1 = cb + (size_t)k1 * DDIM;
        const float* c2 = cb + (size_t)k2 * DDIM;
        double p1 = fma((double)za, (double)c1[lane],
                        (double)zb * (double)c1[lane + 64]);
        double p2 = fma((double)za, (double)c2[lane],
                        (double)zb * (double)c2[lane + 64]);
        for (int off = 32; off; off >>= 1) {
            p1 += __shfl_xor(p1, off, 64);
            p2 += __shfl_xor(p2, off, 64);
        }
        float u1 = (float)(2.0 * p1), u2 = (float)(2.0 * p2);
        float D1, D2;
        {
#pragma clang fp contract(off)
            float t1 = Apair + Bsum[k1];
            float t2 = Apair + Bsum[k2];
            D1 = t1 - u1; D2 = t2 - u2;
        }
        int wk = (D1 < D2 || (D1 == D2 && k1 < k2)) ? k1 : k2;
        if (lane == 0) idx[pix] = wk;
    }
}

// ---------------------------------------------------------------------------
// phase3b: exact full-scan resolve for >=3-candidate pixels (rare) -> fix
// idx[pix]. One wave per item; fp32 prefilter over all 1024 codes (16/lane),
// candidates within smin+BAND get the exact fp64 path. Candidate loop fully
// unrolled: est[]/dot[] stay in registers (runtime indexing -> scratch).
// Runs after phase3a so its idx writes win.
// ---------------------------------------------------------------------------
__global__ __launch_bounds__(256, 2) void phase3b_kernel(
    const float* __restrict__ z, const float* __restrict__ cb,
    const float* __restrict__ Bsum, int* __restrict__ idx,
    const int* __restrict__ cntB, const int* __restrict__ listB)
{
    __shared__ float zsh[4][128];
    const int tid = threadIdx.x, lane = tid & 63, wv = tid >> 6;
    int gwave = (blockIdx.x * 256 + tid) >> 6;
    int nwaves = gridDim.x * 4;
    int nitems = *cntB; if (nitems > CAP_B) nitems = CAP_B;

    for (int item = gwave; item < nitems; item += nwaves) {
        int pix = listB[item];
        int b = pix >> 12, h = (pix >> 6) & 63, w = pix & 63;
        const float* zp = z + (size_t)b * BSTRIDE + h * HW + w;

        float za = zp[(size_t)lane * PLANE];
        float zb = zp[(size_t)(lane + 64) * PLANE];
        zsh[wv][lane] = za;                    // wave-internal: in-order LDS
        zsh[wv][lane + 64] = zb;
        const float* zr = zsh[wv];

        float Apair;
        {
#pragma clang fp contract(off)
            float r0,r1,r2,r3,r4,r5,r6,r7;
            r0 = zr[0]*zr[0]; r1 = zr[1]*zr[1]; r2 = zr[2]*zr[2]; r3 = zr[3]*zr[3];
            r4 = zr[4]*zr[4]; r5 = zr[5]*zr[5]; r6 = zr[6]*zr[6]; r7 = zr[7]*zr[7];
#pragma unroll
            for (int i = 8; i < DDIM; i += 8) {
                r0 += zr[i+0]*zr[i+0]; r1 += zr[i+1]*zr[i+1];
                r2 += zr[i+2]*zr[i+2]; r3 += zr[i+3]*zr[i+3];
                r4 += zr[i+4]*zr[i+4]; r5 += zr[i+5]*zr[i+5];
                r6 += zr[i+6]*zr[i+6]; r7 += zr[i+7]*zr[i+7];
            }
            Apair = ((r0+r1)+(r2+r3)) + ((r4+r5)+(r6+r7));
        }

        // fp32 prefilter: lane owns codes k = g*64+lane, g=0..15
        float dot[16];
#pragma unroll
        for (int g = 0; g < 16; ++g) dot[g] = 0.0f;
        for (int i = 0; i < 32; ++i) {
            f32x4 zv = *(const f32x4*)(zr + i * 4);   // broadcast LDS read
#pragma unroll
            for (int g = 0; g < 16; ++g) {
                const f32x4 cv = *(const f32x4*)(cb + (size_t)(g * 64 + lane) * DDIM + i * 4);
                dot[g] = __builtin_fmaf(zv[0], cv[0],
                         __builtin_fmaf(zv[1], cv[1],
                         __builtin_fmaf(zv[2], cv[2],
                         __builtin_fmaf(zv[3], cv[3], dot[g]))));
            }
        }
        float est[16]; float smin = 3.4e38f;
#pragma unroll
        for (int g = 0; g < 16; ++g) {
            est[g] = Bsum[g * 64 + lane] - 2.0f * dot[g];
            smin = fminf(smin, est[g]);
        }
        for (int off = 32; off; off >>= 1)
            smin = fminf(smin, __shfl_xor(smin, off, 64));

        float bd = 3.4e38f; int bk = 1 << 30;
#pragma unroll
        for (int g = 0; g < 16; ++g) {
            if (est[g] <= smin + BAND) {
                int k = g * 64 + lane;
                const float* c = cb + (size_t)k * DDIM;
                double p = 0.0;
                for (int i = 0; i < DDIM; ++i)
                    p = fma((double)zr[i], (double)c[i], p);
                float Dk;
                {
#pragma clang fp contract(off)
                    float t1 = Apair + Bsum[k];
                    float u = (float)(2.0 * p);
                    Dk = t1 - u;
                }
                if (Dk < bd || (Dk == bd && k < bk)) { bd = Dk; bk = k; }
            }
        }
        for (int off = 32; off; off >>= 1) {
            float od = __shfl_xor(bd, off, 64);
            int   ok = __shfl_xor(bk, off, 64);
            bool better = (od < bd) || (od == bd && ok < bk);
            bd = better ? od : bd;
            bk = better ? ok : bk;
        }
        if (lane == 0) idx[pix] = bk;
    }
}

// ---------------------------------------------------------------------------
// expand: out[b,:,h,w] = cb[idx[pix]]. Block = one (b,h) row; lane = w so
// every store instruction writes one full 256-B contiguous w-row (no RMW,
// no partial lines). cb gather per block touches <=32 KB -> L1-resident.
// ---------------------------------------------------------------------------
__global__ __launch_bounds__(256) void expand_kernel(
    const float* __restrict__ cb, const int* __restrict__ idx,
    float* __restrict__ out)
{
    const int blk = blockIdx.x;                // 2048 = b*64 + h
    const int b = blk >> 6, h = blk & 63;
    const int tid = threadIdx.x, w = tid & 63, wv = tid >> 6;
    const int id = idx[blk * 64 + w];          // same 64 ids per wave (L1)
    const float* crow = cb + (size_t)id * DDIM;
    float* ob = out + (size_t)b * BSTRIDE + h * HW + w;
#pragma unroll
    for (int d0 = 0; d0 < 32; d0 += 4) {
        int d = wv * 32 + d0;
        f32x4 v = *(const f32x4*)(crow + d);   // 16B gather per lane
        ob[(size_t)(d + 0) * PLANE] = v[0];
        ob[(size_t)(d + 1) * PLANE] = v[1];
        ob[(size_t)(d + 2) * PLANE] = v[2];
        ob[(size_t)(d + 3) * PLANE] = v[3];
    }
}

// ---------------------------------------------------------------------------
extern "C" void kernel_launch(void* const* d_in, const int* in_sizes, int n_in,
                              void* d_out, int out_size, void* d_ws, size_t ws_size,
                              hipStream_t stream) {
    const float* z  = (const float*)d_in[0];
    const float* cb = (const float*)d_in[1];
    float* out = (float*)d_out;

    // ws: Bsum 4K | Bs1024 4K | cnts 4K | bs16 256K | listA 512K | listB 32K
    //     | idx 512K
    float* Bsum   = (float*)d_ws;
    float* Bs1024 = (float*)((char*)d_ws + 4096);
    int*   cnts   = (int*)((char*)d_ws + 8192);
    _Float16* bs16 = (_Float16*)((char*)d_ws + 12288);
    int2*  listA  = (int2*)((char*)d_ws + 12288 + 262144);
    int*   listB  = (int*)((char*)d_ws + 12288 + 262144 + 524288);
    int*   idx    = (int*)((char*)d_ws + 12288 + 262144 + 524288 + 32768);
    int* cntA = cnts; int* cntB = cnts + 1;

    prep_kernel<<<68, 256, 0, stream>>>(cb, Bsum, Bs1024, bs16, cnts);
    phase1_mfma<<<NPIX / 128, 256, 0, stream>>>(z, bs16, Bs1024, idx,
                                                cntA, listA, cntB, listB);
    phase3a_kernel<<<1024, 256, 0, stream>>>(z, cb, Bsum, idx, cntA, listA);
    phase3b_kernel<<<128, 256, 0, stream>>>(z, cb, Bsum, idx, cntB, listB);
    expand_kernel<<<2048, 256, 0, stream>>>(cb, idx, out);
}

// Round 9
// 391.855 us; speedup vs baseline: 1.7444x; 1.5699x over previous
//
#include <hip/hip_runtime.h>

#define KCODES 1024
#define DDIM 128
#define HW 64
#define NPIX (32 * HW * HW)         // 131072 pixels
#define PLANE (HW * HW)             // 4096
#define BSTRIDE (DDIM * PLANE)      // 524288 floats per batch image
#define CAP_A 65536
#define CAP_B 8192
// phase1 computes 1024*(Bsum_k - 2 z.c): codebook pre-scaled by exactly 1024
// (pow2, error-free) to fp16; z split into fp16 hi+lo (-2z = zh+zl exact to
// ~2^-22 rel), 2 chained MFMAs per K-chunk. Residual error = c's fp16
// rounding only: sd ~3e-3 scaled, 6-sigma 0.02. Flag margin must cover
// 2*phase1err + ref fp32 band (0.031 scaled) ~= 0.071 -> MARGIN_SC = 0.10.
// k* provably in top-3 when flagged (else contradiction with margin) ->
// 2-cand exact resolve (listA) + >=3-cand full scan (listB, ~0.25%).
// phase1/3a/3b produce INDICES only; expand materializes out with full-line
// stores. phase1 is barrier-free + LDS-free: B streams from L2-resident
// 256KB fragment buffer (R8 post-mortem: 32 barrier drains at 2 blocks/CU
// left waves 97% stalled; no rendezvous -> per-wave vmcnt only).
#define MARGIN_SC 0.10f
#define BAND 1e-4f                  // phase3b fp32-prefilter band (unscaled)

typedef __attribute__((ext_vector_type(8)))  _Float16 f16x8;  // MFMA A/B frag
typedef __attribute__((ext_vector_type(4)))  float    f32x4;
typedef __attribute__((ext_vector_type(16))) float    f32x16; // 32x32 C/D

// ---------------------------------------------------------------------------
// prep: blocks 0..3  -> Bsum[k] (numpy-pairwise, contract off) + 1024*Bsum
//       blocks 4..67 -> codebook*1024 as fp16 in 32x32x16 MFMA B-frag order
// frag layout: half off = ((c*8+s)*64 + l)*8 + j   (c=tile of 32 codes,
// s=kchunk of 16; lane l holds B[k=s*16+(l>>5)*8+j][n=c*32+(l&31)]).
// block 0 thread 0 also zeroes cntA/cntB (prep completes before phase1).
// ---------------------------------------------------------------------------
__global__ __launch_bounds__(256) void prep_kernel(const float* __restrict__ cb,
                                                   float* __restrict__ Bsum,
                                                   float* __restrict__ Bs1024,
                                                   _Float16* __restrict__ bs16,
                                                   int* __restrict__ cnts) {
    int bid = blockIdx.x;
    if (bid < 4) {
        if (bid == 0 && threadIdx.x == 0) { cnts[0] = 0; cnts[1] = 0; }
        {
#pragma clang fp contract(off)
            int k = bid * 256 + threadIdx.x;
            const float* row = cb + k * DDIM;
            float r0,r1,r2,r3,r4,r5,r6,r7;
            r0 = row[0]*row[0]; r1 = row[1]*row[1]; r2 = row[2]*row[2]; r3 = row[3]*row[3];
            r4 = row[4]*row[4]; r5 = row[5]*row[5]; r6 = row[6]*row[6]; r7 = row[7]*row[7];
#pragma unroll
            for (int i = 8; i < DDIM; i += 8) {
                r0 += row[i+0]*row[i+0]; r1 += row[i+1]*row[i+1];
                r2 += row[i+2]*row[i+2]; r3 += row[i+3]*row[i+3];
                r4 += row[i+4]*row[i+4]; r5 += row[i+5]*row[i+5];
                r6 += row[i+6]*row[i+6]; r7 += row[i+7]*row[i+7];
            }
            float bs = ((r0+r1)+(r2+r3)) + ((r4+r5)+(r6+r7));
            Bsum[k] = bs;
            Bs1024[k] = 1024.0f * bs;          // pow2 scale: exact
        }
    } else {
        int t = (bid - 4) * 256 + threadIdx.x; // 16384 = 32c * 8s * 64l
        int c = t >> 9, s = (t >> 6) & 7, l = t & 63;
        int n = l & 31, half = l >> 5;
        int code = c * 32 + n;
        int d0 = s * 16 + half * 8;
        const float* row = cb + code * DDIM + d0;
        f32x4 f0 = *(const f32x4*)(row);
        f32x4 f1 = *(const f32x4*)(row + 4);
        f16x8 v;
#pragma unroll
        for (int e = 0; e < 4; ++e) {
            v[e]     = (_Float16)(1024.0f * f0[e]);   // RNE cvt
            v[4 + e] = (_Float16)(1024.0f * f1[e]);
        }
        *(f16x8*)(bs16 + ((size_t)((c * 8 + s) * 64 + l)) * 8) = v;
    }
}

// ---------------------------------------------------------------------------
// phase1: fp16 z-split 32x32x16 MFMA distance (scaled by 1024) + top-3
// argmin. 4 independent waves/block, 32 px each; NO loop barriers, NO LDS
// staging: B fragments stream from L2 (coalesced dwordx4; every wave reads
// the same 256KB -> per-XCD L2 copies). acc init = 1024*Bsum[k] (L1-res).
// 2 MFMAs/chunk: acc += zh.b + zl.b. Tracking: med3-based sorted-3 insert.
// Tracks (m1,i1,m2,i2,m3): m2-m1<=M -> listA{pix,k1,k2}; m3-m1<=M -> listB.
// C/D: col(code)=lane&31, row(pixel)=(r&3)+8*(r>>2)+4*(lane>>5).
// ---------------------------------------------------------------------------
__global__ __launch_bounds__(256, 2) void phase1_mfma(
    const float* __restrict__ z, const _Float16* __restrict__ bs16,
    const float* __restrict__ Bs1024, int* __restrict__ idx,
    int* __restrict__ cntA, int2* __restrict__ listA,
    int* __restrict__ cntB, int* __restrict__ listB)
{
    __shared__ int idxb[128];
    const int tid = threadIdx.x;
    const int lane = tid & 63, wv = tid >> 6;
    const int gw = blockIdx.x * 4 + wv;        // global wave id, 4096 total
    const int b = gw >> 7;
    const int h = (gw >> 1) & 63;
    const int w0 = (gw & 1) * 32;
    const int col = lane & 31, half = lane >> 5;

    // A fragments: pixel m=col -> w=w0+col; chunk s covers d=s*16+half*8+e.
    // -2z split into fp16 hi+lo (exact to ~2^-22 rel).
    const float* zbase = z + (size_t)b * BSTRIDE + h * HW + w0 + col;
    f16x8 zh[8], zl[8];
#pragma unroll
    for (int s = 0; s < 8; ++s) {
        const float* zp = zbase + (size_t)(s * 16 + half * 8) * PLANE;
        f16x8 hi, lo;
#pragma unroll
        for (int e = 0; e < 8; ++e) {
            float a = -2.0f * zp[(size_t)e * PLANE];
            _Float16 ah = (_Float16)a;
            hi[e] = ah;
            lo[e] = (_Float16)(a - (float)ah);
        }
        zh[s] = hi; zl[s] = lo;
    }

    float m1[16], m2[16], m3[16]; int i1[16], i2[16];
#pragma unroll
    for (int r = 0; r < 16; ++r) {
        m1[r] = 3.4e38f; m2[r] = 3.4e38f; m3[r] = 3.4e38f; i1[r] = 0; i2[r] = 0;
    }

    const f16x8* bfrag = (const f16x8*)bs16;
    for (int c = 0; c < 32; ++c) {
        int kcol = c * 32 + col;
        float bsv = Bs1024[kcol];              // 4KB table, L1-resident
        f32x16 acc;
#pragma unroll
        for (int r = 0; r < 16; ++r) acc[r] = bsv;
#pragma unroll
        for (int s = 0; s < 8; ++s) {
            f16x8 bh = bfrag[(c * 8 + s) * 64 + lane];   // coalesced dwordx4
            acc = __builtin_amdgcn_mfma_f32_32x32x16_f16(zh[s], bh, acc, 0, 0, 0);
            acc = __builtin_amdgcn_mfma_f32_32x32x16_f16(zl[s], bh, acc, 0, 0, 0);
        }
        // sorted-3 insert: med3 for values, cndmask for indices (~8 ops/row)
#pragma unroll
        for (int r = 0; r < 16; ++r) {
            float dv = acc[r];
            bool lt1 = dv < m1[r];
            bool lt2 = dv < m2[r];
            m3[r] = __builtin_amdgcn_fmed3f(m2[r], m3[r], dv);
            m2[r] = __builtin_amdgcn_fmed3f(m1[r], m2[r], dv);
            i2[r] = lt1 ? i1[r] : (lt2 ? kcol : i2[r]);
            i1[r] = lt1 ? kcol : i1[r];
            m1[r] = fminf(m1[r], dv);
        }
    }

    // merge sorted-3 tuples across the 32 lanes (code columns) per row set
#pragma unroll
    for (int mask = 1; mask <= 16; mask <<= 1) {
#pragma unroll
        for (int r = 0; r < 16; ++r) {
            float b1 = __shfl_xor(m1[r], mask, 64);
            float b2 = __shfl_xor(m2[r], mask, 64);
            float b3 = __shfl_xor(m3[r], mask, 64);
            int  ib1 = __shfl_xor(i1[r], mask, 64);
            int  ib2 = __shfl_xor(i2[r], mask, 64);
            float a1 = m1[r], a2 = m2[r], a3 = m3[r];
            int  ia1 = i1[r], ia2 = i2[r];
            bool bfi = (b1 < a1) || (b1 == a1 && ib1 < ia1);
            float x1 = bfi ? b1 : a1;  int xi1 = bfi ? ib1 : ia1;
            float x2 = bfi ? b2 : a2;  int xi2 = bfi ? ib2 : ia2;
            float x3 = bfi ? b3 : a3;
            float y1 = bfi ? a1 : b1;  int yi1 = bfi ? ia1 : ib1;
            float y2 = bfi ? a2 : b2;
            bool ys = (y1 < x2) || (y1 == x2 && yi1 < xi2);
            m1[r] = x1; i1[r] = xi1;
            m2[r] = ys ? y1 : x2;  i2[r] = ys ? yi1 : xi2;
            m3[r] = ys ? fminf(x2, y2) : fminf(x3, y1);
        }
    }

    if (col == 0) {                  // 2 writer lanes per wave (half=0/1)
#pragma unroll
        for (int r = 0; r < 16; ++r) {
            int row = (r & 3) + 8 * (r >> 2) + 4 * half;
            idxb[wv * 32 + row] = i1[r];
            if (m2[r] - m1[r] <= MARGIN_SC) {           // ambiguous
                int pix = gw * 32 + row;
                int pos = atomicAdd(cntA, 1);
                if (pos < CAP_A) {
                    int2 rec; rec.x = pix; rec.y = i1[r] | (i2[r] << 16);
                    listA[pos] = rec;
                }
                if (m3[r] - m1[r] <= MARGIN_SC) {       // >=3 cands (rare)
                    int pb = atomicAdd(cntB, 1);
                    if (pb < CAP_B) listB[pb] = pix;
                }
            }
        }
    }
    __syncthreads();                 // single end-of-kernel rendezvous

    if (tid < 128) idx[blockIdx.x * 128 + tid] = idxb[tid];  // coalesced dump
}

// ---------------------------------------------------------------------------
// phase3a: resolve 2-candidate ambiguous pixels -> fix idx[pix]. One wave
// per item.  A = numpy-pairwise sum of z^2 (fp32, contract off); p = fp64
// dot (lane-split + shuffle reduce); D_k = fl32(fl32(A+Bsum_k) - fl32(2p));
// winner = lex min (D, k). No __syncthreads in item loop (waves diverge).
// ---------------------------------------------------------------------------
__global__ __launch_bounds__(256, 4) void phase3a_kernel(
    const float* __restrict__ z, const float* __restrict__ cb,
    const float* __restrict__ Bsum, int* __restrict__ idx,
    const int* __restrict__ cntA, const int2* __restrict__ listA)
{
    __shared__ float zsh[4][128];
    const int tid = threadIdx.x, lane = tid & 63, wv = tid >> 6;
    int gwave = (blockIdx.x * 256 + tid) >> 6;
    int nwaves = gridDim.x * 4;
    int nitems = *cntA; if (nitems > CAP_A) nitems = CAP_A;

    for (int item = gwave; item < nitems; item += nwaves) {
        int2 rec = listA[item];
        int pix = rec.x;
        int k1 = rec.y & 0xFFFF, k2 = rec.y >> 16;
        int b = pix >> 12, h = (pix >> 6) & 63, w = pix & 63;
        const float* zp = z + (size_t)b * BSTRIDE + h * HW + w;

        float za = zp[(size_t)lane * PLANE];
        float zb = zp[(size_t)(lane + 64) * PLANE];
        zsh[wv][lane] = za;
        zsh[wv][lane + 64] = zb;

        float Apair;
        {
#pragma clang fp contract(off)
            const float* zr = zsh[wv];
            float r0,r1,r2,r3,r4,r5,r6,r7;
            r0 = zr[0]*zr[0]; r1 = zr[1]*zr[1]; r2 = zr[2]*zr[2]; r3 = zr[3]*zr[3];
            r4 = zr[4]*zr[4]; r5 = zr[5]*zr[5]; r6 = zr[6]*zr[6]; r7 = zr[7]*zr[7];
#pragma unroll
            for (int i = 8; i < DDIM; i += 8) {
                r0 += zr[i+0]*zr[i+0]; r1 += zr[i+1]*zr[i+1];
                r2 += zr[i+2]*zr[i+2]; r3 += zr[i+3]*zr[i+3];
                r4 += zr[i+4]*zr[i+4]; r5 += zr[i+5]*zr[i+5];
                r6 += zr[i+6]*zr[i+6]; r7 += zr[i+7]*zr[i+7];
            }
            Apair = ((r0+r1)+(r2+r3)) + ((r4+r5)+(r6+r7));
        }

        const float* c1 = cb + (size_t)k1 * DDIM;
        const float* c2 = cb + (size_t)k2 * DDIM;
        double p1 = fma((double)za, (double)c1[lane],
                        (double)zb * (double)c1[lane + 64]);
        double p2 = fma((double)za, (double)c2[lane],
                        (double)zb * (double)c2[lane + 64]);
        for (int off = 32; off; off >>= 1) {
            p1 += __shfl_xor(p1, off, 64);
            p2 += __shfl_xor(p2, off, 64);
        }
        float u1 = (float)(2.0 * p1), u2 = (float)(2.0 * p2);
        float D1, D2;
        {
#pragma clang fp contract(off)
            float t1 = Apair + Bsum[k1];
            float t2 = Apair + Bsum[k2];
            D1 = t1 - u1; D2 = t2 - u2;
        }
        int wk = (D1 < D2 || (D1 == D2 && k1 < k2)) ? k1 : k2;
        if (lane == 0) idx[pix] = wk;
    }
}

// ---------------------------------------------------------------------------
// phase3b: exact full-scan resolve for >=3-candidate pixels (rare) -> fix
// idx[pix]. One wave per item; fp32 prefilter over all 1024 codes (16/lane),
// candidates within smin+BAND get the exact fp64 path. Fully unrolled so
// est[]/dot[] stay in registers. Runs after phase3a so its idx writes win.
// ---------------------------------------------------------------------------
__global__ __launch_bounds__(256, 2) void phase3b_kernel(
    const float* __restrict__ z, const float* __restrict__ cb,
    const float* __restrict__ Bsum, int* __restrict__ idx,
    const int* __restrict__ cntB, const int* __restrict__ listB)
{
    __shared__ float zsh[4][128];
    const int tid = threadIdx.x, lane = tid & 63, wv = tid >> 6;
    int gwave = (blockIdx.x * 256 + tid) >> 6;
    int nwaves = gridDim.x * 4;
    int nitems = *cntB; if (nitems > CAP_B) nitems = CAP_B;

    for (int item = gwave; item < nitems; item += nwaves) {
        int pix = listB[item];
        int b = pix >> 12, h = (pix >> 6) & 63, w = pix & 63;
        const float* zp = z + (size_t)b * BSTRIDE + h * HW + w;

        float za = zp[(size_t)lane * PLANE];
        float zb = zp[(size_t)(lane + 64) * PLANE];
        zsh[wv][lane] = za;                    // wave-internal: in-order LDS
        zsh[wv][lane + 64] = zb;
        const float* zr = zsh[wv];

        float Apair;
        {
#pragma clang fp contract(off)
            float r0,r1,r2,r3,r4,r5,r6,r7;
            r0 = zr[0]*zr[0]; r1 = zr[1]*zr[1]; r2 = zr[2]*zr[2]; r3 = zr[3]*zr[3];
            r4 = zr[4]*zr[4]; r5 = zr[5]*zr[5]; r6 = zr[6]*zr[6]; r7 = zr[7]*zr[7];
#pragma unroll
            for (int i = 8; i < DDIM; i += 8) {
                r0 += zr[i+0]*zr[i+0]; r1 += zr[i+1]*zr[i+1];
                r2 += zr[i+2]*zr[i+2]; r3 += zr[i+3]*zr[i+3];
                r4 += zr[i+4]*zr[i+4]; r5 += zr[i+5]*zr[i+5];
                r6 += zr[i+6]*zr[i+6]; r7 += zr[i+7]*zr[i+7];
            }
            Apair = ((r0+r1)+(r2+r3)) + ((r4+r5)+(r6+r7));
        }

        // fp32 prefilter: lane owns codes k = g*64+lane, g=0..15
        float dot[16];
#pragma unroll
        for (int g = 0; g < 16; ++g) dot[g] = 0.0f;
        for (int i = 0; i < 32; ++i) {
            f32x4 zv = *(const f32x4*)(zr + i * 4);   // broadcast LDS read
#pragma unroll
            for (int g = 0; g < 16; ++g) {
                const f32x4 cv = *(const f32x4*)(cb + (size_t)(g * 64 + lane) * DDIM + i * 4);
                dot[g] = __builtin_fmaf(zv[0], cv[0],
                         __builtin_fmaf(zv[1], cv[1],
                         __builtin_fmaf(zv[2], cv[2],
                         __builtin_fmaf(zv[3], cv[3], dot[g]))));
            }
        }
        float est[16]; float smin = 3.4e38f;
#pragma unroll
        for (int g = 0; g < 16; ++g) {
            est[g] = Bsum[g * 64 + lane] - 2.0f * dot[g];
            smin = fminf(smin, est[g]);
        }
        for (int off = 32; off; off >>= 1)
            smin = fminf(smin, __shfl_xor(smin, off, 64));

        float bd = 3.4e38f; int bk = 1 << 30;
#pragma unroll
        for (int g = 0; g < 16; ++g) {
            if (est[g] <= smin + BAND) {
                int k = g * 64 + lane;
                const float* c = cb + (size_t)k * DDIM;
                double p = 0.0;
                for (int i = 0; i < DDIM; ++i)
                    p = fma((double)zr[i], (double)c[i], p);
                float Dk;
                {
#pragma clang fp contract(off)
                    float t1 = Apair + Bsum[k];
                    float u = (float)(2.0 * p);
                    Dk = t1 - u;
                }
                if (Dk < bd || (Dk == bd && k < bk)) { bd = Dk; bk = k; }
            }
        }
        for (int off = 32; off; off >>= 1) {
            float od = __shfl_xor(bd, off, 64);
            int   ok = __shfl_xor(bk, off, 64);
            bool better = (od < bd) || (od == bd && ok < bk);
            bd = better ? od : bd;
            bk = better ? ok : bk;
        }
        if (lane == 0) idx[pix] = bk;
    }
}

// ---------------------------------------------------------------------------
// expand: out[b,:,h,w] = cb[idx[pix]]. Block = one (b,h) row; lane = w so
// every store instruction writes one full 256-B contiguous w-row (no RMW,
// no partial lines). cb gather per block touches <=32 KB -> L1-resident.
// ---------------------------------------------------------------------------
__global__ __launch_bounds__(256) void expand_kernel(
    const float* __restrict__ cb, const int* __restrict__ idx,
    float* __restrict__ out)
{
    const int blk = blockIdx.x;                // 2048 = b*64 + h
    const int b = blk >> 6, h = blk & 63;
    const int tid = threadIdx.x, w = tid & 63, wv = tid >> 6;
    const int id = idx[blk * 64 + w];          // same 64 ids per wave (L1)
    const float* crow = cb + (size_t)id * DDIM;
    float* ob = out + (size_t)b * BSTRIDE + h * HW + w;
#pragma unroll
    for (int d0 = 0; d0 < 32; d0 += 4) {
        int d = wv * 32 + d0;
        f32x4 v = *(const f32x4*)(crow + d);   // 16B gather per lane
        ob[(size_t)(d + 0) * PLANE] = v[0];
        ob[(size_t)(d + 1) * PLANE] = v[1];
        ob[(size_t)(d + 2) * PLANE] = v[2];
        ob[(size_t)(d + 3) * PLANE] = v[3];
    }
}

// ---------------------------------------------------------------------------
extern "C" void kernel_launch(void* const* d_in, const int* in_sizes, int n_in,
                              void* d_out, int out_size, void* d_ws, size_t ws_size,
                              hipStream_t stream) {
    const float* z  = (const float*)d_in[0];
    const float* cb = (const float*)d_in[1];
    float* out = (float*)d_out;

    // ws: Bsum 4K | Bs1024 4K | cnts 4K | bs16 256K | listA 512K | listB 32K
    //     | idx 512K
    float* Bsum   = (float*)d_ws;
    float* Bs1024 = (float*)((char*)d_ws + 4096);
    int*   cnts   = (int*)((char*)d_ws + 8192);
    _Float16* bs16 = (_Float16*)((char*)d_ws + 12288);
    int2*  listA  = (int2*)((char*)d_ws + 12288 + 262144);
    int*   listB  = (int*)((char*)d_ws + 12288 + 262144 + 524288);
    int*   idx    = (int*)((char*)d_ws + 12288 + 262144 + 524288 + 32768);
    int* cntA = cnts; int* cntB = cnts + 1;

    prep_kernel<<<68, 256, 0, stream>>>(cb, Bsum, Bs1024, bs16, cnts);
    phase1_mfma<<<NPIX / 128, 256, 0, stream>>>(z, bs16, Bs1024, idx,
                                                cntA, listA, cntB, listB);
    phase3a_kernel<<<1024, 256, 0, stream>>>(z, cb, Bsum, idx, cntA, listA);
    phase3b_kernel<<<128, 256, 0, stream>>>(z, cb, Bsum, idx, cntB, listB);
    expand_kernel<<<2048, 256, 0, stream>>>(cb, idx, out);
}

// Round 10
// 320.231 us; speedup vs baseline: 2.1346x; 1.2237x over previous
//
#include <hip/hip_runtime.h>

#define KCODES 1024
#define DDIM 128
#define HW 64
#define NPIX (32 * HW * HW)         // 131072 pixels
#define PLANE (HW * HW)             // 4096
#define BSTRIDE (DDIM * PLANE)      // 524288 floats per batch image
#define CAP_A 65536
#define CAP_B 8192
// phase1 computes 1024*(Bsum_k - 2 z.c) with a single fp16 16x16x32 MFMA
// per K-chunk (codebook pre-scaled by exactly 1024 -> fp16-normal; pow2
// scale error-free; z cast to fp16 directly). Error budget (scaled):
// c-rounding 6sig ~0.018 + z-rounding 6sig ~0.008 -> err<=0.026; flag
// margin >= 2*err + ref fp32 band 0.033 = 0.085 -> MARGIN_SC 0.15 (1.8x
// headroom). Flagged: 2-cand exact fp64 resolve (listA) / >=3-cand full
// scan (listB). idx-only outputs; expand writes full 256B lines.
// R9 post-mortem: 32x32 tracking state (~180 VGPR) capped occupancy at
// 1.8 waves/SIMD -> 90% latency stall. 16x16 shrinks per-wave state to
// ~65 VGPR -> 6-7 waves/SIMD; B-frag L2 latency hidden by TLP.
#define MARGIN_SC 0.15f
#define BAND 1e-4f                  // phase3b fp32-prefilter band (unscaled)

typedef __attribute__((ext_vector_type(8)))  _Float16 f16x8;  // MFMA A/B frag
typedef __attribute__((ext_vector_type(4)))  float    f32x4;

// ---------------------------------------------------------------------------
// prep: blocks 0..3  -> Bsum[k] (numpy-pairwise, contract off) + 1024*Bsum
//       blocks 4..67 -> codebook*1024 as fp16 in 16x16x32 MFMA B-frag order
// frag layout: half off = ((c*4+s)*64 + l)*8 + j   (c=tile of 16 codes,
// s=kchunk of 32; lane l holds B[k=s*32+(l>>4)*8+j][n=c*16+(l&15)]).
// block 0 thread 0 also zeroes cntA/cntB (prep completes before phase1).
// ---------------------------------------------------------------------------
__global__ __launch_bounds__(256) void prep_kernel(const float* __restrict__ cb,
                                                   float* __restrict__ Bsum,
                                                   float* __restrict__ Bs1024,
                                                   _Float16* __restrict__ bs16,
                                                   int* __restrict__ cnts) {
    int bid = blockIdx.x;
    if (bid < 4) {
        if (bid == 0 && threadIdx.x == 0) { cnts[0] = 0; cnts[1] = 0; }
        {
#pragma clang fp contract(off)
            int k = bid * 256 + threadIdx.x;
            const float* row = cb + k * DDIM;
            float r0,r1,r2,r3,r4,r5,r6,r7;
            r0 = row[0]*row[0]; r1 = row[1]*row[1]; r2 = row[2]*row[2]; r3 = row[3]*row[3];
            r4 = row[4]*row[4]; r5 = row[5]*row[5]; r6 = row[6]*row[6]; r7 = row[7]*row[7];
#pragma unroll
            for (int i = 8; i < DDIM; i += 8) {
                r0 += row[i+0]*row[i+0]; r1 += row[i+1]*row[i+1];
                r2 += row[i+2]*row[i+2]; r3 += row[i+3]*row[i+3];
                r4 += row[i+4]*row[i+4]; r5 += row[i+5]*row[i+5];
                r6 += row[i+6]*row[i+6]; r7 += row[i+7]*row[i+7];
            }
            float bs = ((r0+r1)+(r2+r3)) + ((r4+r5)+(r6+r7));
            Bsum[k] = bs;
            Bs1024[k] = 1024.0f * bs;          // pow2 scale: exact
        }
    } else {
        int t = (bid - 4) * 256 + threadIdx.x; // 16384 = 64c * 4s * 64l
        int c = t >> 8, s = (t >> 6) & 3, l = t & 63;
        int n = l & 15, kg = l >> 4;
        int code = c * 16 + n;
        int d0 = s * 32 + kg * 8;
        const float* row = cb + code * DDIM + d0;
        f32x4 f0 = *(const f32x4*)(row);
        f32x4 f1 = *(const f32x4*)(row + 4);
        f16x8 v;
#pragma unroll
        for (int e = 0; e < 4; ++e) {
            v[e]     = (_Float16)(1024.0f * f0[e]);   // RNE cvt
            v[4 + e] = (_Float16)(1024.0f * f1[e]);
        }
        *(f16x8*)(bs16 + ((size_t)((c * 4 + s) * 64 + l)) * 8) = v;
    }
}

// ---------------------------------------------------------------------------
// phase1: fp16 16x16x32 MFMA distance (scaled by 1024) + top-3 argmin.
// Wave owns 16 px (one w-run); 8192 waves, 4 independent waves/block, NO
// loop barriers, NO LDS staging: B fragments stream from L2/L1 (the 4
// waves of a block walk the same 256KB in loose lockstep -> L1 reuse).
// acc init = 1024*Bsum[k] (4KB, L1-resident). Low VGPR (~65) -> high
// occupancy hides the fragment-load latency (R9 lesson).
// A: m=lane&15 -> w=w0+m, k=(lane>>4)*8+e (K=32/chunk, 4 chunks).
// C/D: col(code)=lane&15, row(pixel)=(lane>>4)*4+r.
// Tracks (m1,i1,m2,i2,m3): m2-m1<=M -> listA{pix,k1,k2}; m3-m1<=M -> listB.
// ---------------------------------------------------------------------------
__global__ __launch_bounds__(256, 6) void phase1_mfma(
    const float* __restrict__ z, const _Float16* __restrict__ bs16,
    const float* __restrict__ Bs1024, int* __restrict__ idx,
    int* __restrict__ cntA, int2* __restrict__ listA,
    int* __restrict__ cntB, int* __restrict__ listB)
{
    __shared__ int idxb[64];
    const int tid = threadIdx.x;
    const int lane = tid & 63, wv = tid >> 6;
    const int gw = blockIdx.x * 4 + wv;        // 8192 waves, 16 px each
    const int b = gw >> 8;
    const int rem = gw & 255;
    const int h = rem >> 2;
    const int w0 = (rem & 3) * 16;
    const int col = lane & 15, kg = lane >> 4;

    // A fragments: pixel m=col -> w=w0+col; chunk s covers d=s*32+kg*8+e
    const float* zbase = z + (size_t)b * BSTRIDE + h * HW + w0 + col;
    f16x8 za[4];
#pragma unroll
    for (int s = 0; s < 4; ++s) {
        const float* zp = zbase + (size_t)(s * 32 + kg * 8) * PLANE;
        f16x8 a;
#pragma unroll
        for (int e = 0; e < 8; ++e)
            a[e] = (_Float16)(-2.0f * zp[(size_t)e * PLANE]);
        za[s] = a;
    }

    float m1[4], m2[4], m3[4]; int i1[4], i2[4];
#pragma unroll
    for (int r = 0; r < 4; ++r) {
        m1[r] = 3.4e38f; m2[r] = 3.4e38f; m3[r] = 3.4e38f; i1[r] = 0; i2[r] = 0;
    }

    const f16x8* bfrag = (const f16x8*)bs16;
    for (int c = 0; c < 64; ++c) {             // 16-code tiles
        int kcol = c * 16 + col;
        float bsv = Bs1024[kcol];              // 4KB table, L1-resident
        f32x4 acc = { bsv, bsv, bsv, bsv };
#pragma unroll
        for (int s = 0; s < 4; ++s) {
            f16x8 bh = bfrag[(c * 4 + s) * 64 + lane];   // coalesced dwordx4
            acc = __builtin_amdgcn_mfma_f32_16x16x32_f16(za[s], bh, acc, 0, 0, 0);
        }
        // sorted-3 insert: med3 for values, cndmask for indices
#pragma unroll
        for (int r = 0; r < 4; ++r) {
            float dv = acc[r];
            bool lt1 = dv < m1[r];
            bool lt2 = dv < m2[r];
            m3[r] = __builtin_amdgcn_fmed3f(m2[r], m3[r], dv);
            m2[r] = __builtin_amdgcn_fmed3f(m1[r], m2[r], dv);
            i2[r] = lt1 ? i1[r] : (lt2 ? kcol : i2[r]);
            i1[r] = lt1 ? kcol : i1[r];        // strict < keeps lowest index
            m1[r] = fminf(m1[r], dv);
        }
    }

    // merge sorted-3 tuples across the 16 lanes (code columns) per row group
#pragma unroll
    for (int mask = 1; mask <= 8; mask <<= 1) {
#pragma unroll
        for (int r = 0; r < 4; ++r) {
            float b1 = __shfl_xor(m1[r], mask, 64);
            float b2 = __shfl_xor(m2[r], mask, 64);
            float b3 = __shfl_xor(m3[r], mask, 64);
            int  ib1 = __shfl_xor(i1[r], mask, 64);
            int  ib2 = __shfl_xor(i2[r], mask, 64);
            float a1 = m1[r], a2 = m2[r], a3 = m3[r];
            int  ia1 = i1[r], ia2 = i2[r];
            bool bfi = (b1 < a1) || (b1 == a1 && ib1 < ia1);
            float x1 = bfi ? b1 : a1;  int xi1 = bfi ? ib1 : ia1;
            float x2 = bfi ? b2 : a2;  int xi2 = bfi ? ib2 : ia2;
            float x3 = bfi ? b3 : a3;
            float y1 = bfi ? a1 : b1;  int yi1 = bfi ? ia1 : ib1;
            float y2 = bfi ? a2 : b2;
            bool ys = (y1 < x2) || (y1 == x2 && yi1 < xi2);
            m1[r] = x1; i1[r] = xi1;
            m2[r] = ys ? y1 : x2;  i2[r] = ys ? yi1 : xi2;
            m3[r] = ys ? fminf(x2, y2) : fminf(x3, y1);
        }
    }

    if (col == 0) {                  // 4 writer lanes/wave; rows kg*4+r
#pragma unroll
        for (int r = 0; r < 4; ++r) {
            int row = kg * 4 + r;
            idxb[wv * 16 + row] = i1[r];
            if (m2[r] - m1[r] <= MARGIN_SC) {           // ambiguous
                int pix = gw * 16 + row;
                int pos = atomicAdd(cntA, 1);
                if (pos < CAP_A) {
                    int2 rec; rec.x = pix; rec.y = i1[r] | (i2[r] << 16);
                    listA[pos] = rec;
                }
                if (m3[r] - m1[r] <= MARGIN_SC) {       // >=3 cands (rare)
                    int pb = atomicAdd(cntB, 1);
                    if (pb < CAP_B) listB[pb] = pix;
                }
            }
        }
    }
    __syncthreads();                 // single end-of-kernel rendezvous

    if (tid < 64) idx[blockIdx.x * 64 + tid] = idxb[tid];  // coalesced dump
}

// ---------------------------------------------------------------------------
// phase3a: resolve 2-candidate ambiguous pixels -> fix idx[pix]. One wave
// per item.  A = numpy-pairwise sum of z^2 (fp32, contract off); p = fp64
// dot (lane-split + shuffle reduce); D_k = fl32(fl32(A+Bsum_k) - fl32(2p));
// winner = lex min (D, k). No __syncthreads in item loop (waves diverge).
// ---------------------------------------------------------------------------
__global__ __launch_bounds__(256, 4) void phase3a_kernel(
    const float* __restrict__ z, const float* __restrict__ cb,
    const float* __restrict__ Bsum, int* __restrict__ idx,
    const int* __restrict__ cntA, const int2* __restrict__ listA)
{
    __shared__ float zsh[4][128];
    const int tid = threadIdx.x, lane = tid & 63, wv = tid >> 6;
    int gwave = (blockIdx.x * 256 + tid) >> 6;
    int nwaves = gridDim.x * 4;
    int nitems = *cntA; if (nitems > CAP_A) nitems = CAP_A;

    for (int item = gwave; item < nitems; item += nwaves) {
        int2 rec = listA[item];
        int pix = rec.x;
        int k1 = rec.y & 0xFFFF, k2 = rec.y >> 16;
        int b = pix >> 12, h = (pix >> 6) & 63, w = pix & 63;
        const float* zp = z + (size_t)b * BSTRIDE + h * HW + w;

        float za = zp[(size_t)lane * PLANE];
        float zb = zp[(size_t)(lane + 64) * PLANE];
        zsh[wv][lane] = za;
        zsh[wv][lane + 64] = zb;

        float Apair;
        {
#pragma clang fp contract(off)
            const float* zr = zsh[wv];
            float r0,r1,r2,r3,r4,r5,r6,r7;
            r0 = zr[0]*zr[0]; r1 = zr[1]*zr[1]; r2 = zr[2]*zr[2]; r3 = zr[3]*zr[3];
            r4 = zr[4]*zr[4]; r5 = zr[5]*zr[5]; r6 = zr[6]*zr[6]; r7 = zr[7]*zr[7];
#pragma unroll
            for (int i = 8; i < DDIM; i += 8) {
                r0 += zr[i+0]*zr[i+0]; r1 += zr[i+1]*zr[i+1];
                r2 += zr[i+2]*zr[i+2]; r3 += zr[i+3]*zr[i+3];
                r4 += zr[i+4]*zr[i+4]; r5 += zr[i+5]*zr[i+5];
                r6 += zr[i+6]*zr[i+6]; r7 += zr[i+7]*zr[i+7];
            }
            Apair = ((r0+r1)+(r2+r3)) + ((r4+r5)+(r6+r7));
        }

        const float* c1 = cb + (size_t)k1 * DDIM;
        const float* c2 = cb + (size_t)k2 * DDIM;
        double p1 = fma((double)za, (double)c1[lane],
                        (double)zb * (double)c1[lane + 64]);
        double p2 = fma((double)za, (double)c2[lane],
                        (double)zb * (double)c2[lane + 64]);
        for (int off = 32; off; off >>= 1) {
            p1 += __shfl_xor(p1, off, 64);
            p2 += __shfl_xor(p2, off, 64);
        }
        float u1 = (float)(2.0 * p1), u2 = (float)(2.0 * p2);
        float D1, D2;
        {
#pragma clang fp contract(off)
            float t1 = Apair + Bsum[k1];
            float t2 = Apair + Bsum[k2];
            D1 = t1 - u1; D2 = t2 - u2;
        }
        int wk = (D1 < D2 || (D1 == D2 && k1 < k2)) ? k1 : k2;
        if (lane == 0) idx[pix] = wk;
    }
}

// ---------------------------------------------------------------------------
// phase3b: exact full-scan resolve for >=3-candidate pixels (rare) -> fix
// idx[pix]. One wave per item; fp32 prefilter over all 1024 codes (16/lane),
// candidates within smin+BAND get the exact fp64 path. Fully unrolled so
// est[]/dot[] stay in registers. Runs after phase3a so its idx writes win.
// ---------------------------------------------------------------------------
__global__ __launch_bounds__(256, 2) void phase3b_kernel(
    const float* __restrict__ z, const float* __restrict__ cb,
    const float* __restrict__ Bsum, int* __restrict__ idx,
    const int* __restrict__ cntB, const int* __restrict__ listB)
{
    __shared__ float zsh[4][128];
    const int tid = threadIdx.x, lane = tid & 63, wv = tid >> 6;
    int gwave = (blockIdx.x * 256 + tid) >> 6;
    int nwaves = gridDim.x * 4;
    int nitems = *cntB; if (nitems > CAP_B) nitems = CAP_B;

    for (int item = gwave; item < nitems; item += nwaves) {
        int pix = listB[item];
        int b = pix >> 12, h = (pix >> 6) & 63, w = pix & 63;
        const float* zp = z + (size_t)b * BSTRIDE + h * HW + w;

        float za = zp[(size_t)lane * PLANE];
        float zb = zp[(size_t)(lane + 64) * PLANE];
        zsh[wv][lane] = za;                    // wave-internal: in-order LDS
        zsh[wv][lane + 64] = zb;
        const float* zr = zsh[wv];

        float Apair;
        {
#pragma clang fp contract(off)
            float r0,r1,r2,r3,r4,r5,r6,r7;
            r0 = zr[0]*zr[0]; r1 = zr[1]*zr[1]; r2 = zr[2]*zr[2]; r3 = zr[3]*zr[3];
            r4 = zr[4]*zr[4]; r5 = zr[5]*zr[5]; r6 = zr[6]*zr[6]; r7 = zr[7]*zr[7];
#pragma unroll
            for (int i = 8; i < DDIM; i += 8) {
                r0 += zr[i+0]*zr[i+0]; r1 += zr[i+1]*zr[i+1];
                r2 += zr[i+2]*zr[i+2]; r3 += zr[i+3]*zr[i+3];
                r4 += zr[i+4]*zr[i+4]; r5 += zr[i+5]*zr[i+5];
                r6 += zr[i+6]*zr[i+6]; r7 += zr[i+7]*zr[i+7];
            }
            Apair = ((r0+r1)+(r2+r3)) + ((r4+r5)+(r6+r7));
        }

        // fp32 prefilter: lane owns codes k = g*64+lane, g=0..15
        float dot[16];
#pragma unroll
        for (int g = 0; g < 16; ++g) dot[g] = 0.0f;
        for (int i = 0; i < 32; ++i) {
            f32x4 zv = *(const f32x4*)(zr + i * 4);   // broadcast LDS read
#pragma unroll
            for (int g = 0; g < 16; ++g) {
                const f32x4 cv = *(const f32x4*)(cb + (size_t)(g * 64 + lane) * DDIM + i * 4);
                dot[g] = __builtin_fmaf(zv[0], cv[0],
                         __builtin_fmaf(zv[1], cv[1],
                         __builtin_fmaf(zv[2], cv[2],
                         __builtin_fmaf(zv[3], cv[3], dot[g]))));
            }
        }
        float est[16]; float smin = 3.4e38f;
#pragma unroll
        for (int g = 0; g < 16; ++g) {
            est[g] = Bsum[g * 64 + lane] - 2.0f * dot[g];
            smin = fminf(smin, est[g]);
        }
        for (int off = 32; off; off >>= 1)
            smin = fminf(smin, __shfl_xor(smin, off, 64));

        float bd = 3.4e38f; int bk = 1 << 30;
#pragma unroll
        for (int g = 0; g < 16; ++g) {
            if (est[g] <= smin + BAND) {
                int k = g * 64 + lane;
                const float* c = cb + (size_t)k * DDIM;
                double p = 0.0;
                for (int i = 0; i < DDIM; ++i)
                    p = fma((double)zr[i], (double)c[i], p);
                float Dk;
                {
#pragma clang fp contract(off)
                    float t1 = Apair + Bsum[k];
                    float u = (float)(2.0 * p);
                    Dk = t1 - u;
                }
                if (Dk < bd || (Dk == bd && k < bk)) { bd = Dk; bk = k; }
            }
        }
        for (int off = 32; off; off >>= 1) {
            float od = __shfl_xor(bd, off, 64);
            int   ok = __shfl_xor(bk, off, 64);
            bool better = (od < bd) || (od == bd && ok < bk);
            bd = better ? od : bd;
            bk = better ? ok : bk;
        }
        if (lane == 0) idx[pix] = bk;
    }
}

// ---------------------------------------------------------------------------
// expand: out[b,:,h,w] = cb[idx[pix]]. Block = one (b,h) row; lane = w so
// every store instruction writes one full 256-B contiguous w-row (no RMW,
// no partial lines). cb gather per block touches <=32 KB -> L1-resident.
// ---------------------------------------------------------------------------
__global__ __launch_bounds__(256) void expand_kernel(
    const float* __restrict__ cb, const int* __restrict__ idx,
    float* __restrict__ out)
{
    const int blk = blockIdx.x;                // 2048 = b*64 + h
    const int b = blk >> 6, h = blk & 63;
    const int tid = threadIdx.x, w = tid & 63, wv = tid >> 6;
    const int id = idx[blk * 64 + w];          // same 64 ids per wave (L1)
    const float* crow = cb + (size_t)id * DDIM;
    float* ob = out + (size_t)b * BSTRIDE + h * HW + w;
#pragma unroll
    for (int d0 = 0; d0 < 32; d0 += 4) {
        int d = wv * 32 + d0;
        f32x4 v = *(const f32x4*)(crow + d);   // 16B gather per lane
        ob[(size_t)(d + 0) * PLANE] = v[0];
        ob[(size_t)(d + 1) * PLANE] = v[1];
        ob[(size_t)(d + 2) * PLANE] = v[2];
        ob[(size_t)(d + 3) * PLANE] = v[3];
    }
}

// ---------------------------------------------------------------------------
extern "C" void kernel_launch(void* const* d_in, const int* in_sizes, int n_in,
                              void* d_out, int out_size, void* d_ws, size_t ws_size,
                              hipStream_t stream) {
    const float* z  = (const float*)d_in[0];
    const float* cb = (const float*)d_in[1];
    float* out = (float*)d_out;

    // ws: Bsum 4K | Bs1024 4K | cnts 4K | bs16 256K | listA 512K | listB 32K
    //     | idx 512K
    float* Bsum   = (float*)d_ws;
    float* Bs1024 = (float*)((char*)d_ws + 4096);
    int*   cnts   = (int*)((char*)d_ws + 8192);
    _Float16* bs16 = (_Float16*)((char*)d_ws + 12288);
    int2*  listA  = (int2*)((char*)d_ws + 12288 + 262144);
    int*   listB  = (int*)((char*)d_ws + 12288 + 262144 + 524288);
    int*   idx    = (int*)((char*)d_ws + 12288 + 262144 + 524288 + 32768);
    int* cntA = cnts; int* cntB = cnts + 1;

    prep_kernel<<<68, 256, 0, stream>>>(cb, Bsum, Bs1024, bs16, cnts);
    phase1_mfma<<<NPIX / 64, 256, 0, stream>>>(z, bs16, Bs1024, idx,
                                               cntA, listA, cntB, listB);
    phase3a_kernel<<<1024, 256, 0, stream>>>(z, cb, Bsum, idx, cntA, listA);
    phase3b_kernel<<<128, 256, 0, stream>>>(z, cb, Bsum, idx, cntB, listB);
    expand_kernel<<<2048, 256, 0, stream>>>(cb, idx, out);
}

// Round 13
// 317.642 us; speedup vs baseline: 2.1520x; 1.0081x over previous
//
#include <hip/hip_runtime.h>

#define KCODES 1024
#define DDIM 128
#define HW 64
#define NPIX (32 * HW * HW)         // 131072 pixels
#define PLANE (HW * HW)             // 4096
#define BSTRIDE (DDIM * PLANE)      // 524288 floats per batch image
#define CAP_A 65536
#define CAP_B 8192
// phase1 computes 1024*(Bsum_k - 2 z.c) with a single fp16 16x16x32 MFMA
// per K-chunk (codebook pre-scaled by exactly 1024 -> fp16-normal; pow2
// scale error-free; z cast to fp16 directly). Error budget (scaled):
// c-rounding 6sig ~0.018 + z-rounding 6sig ~0.008 -> err<=0.026; flag
// margin >= 2*err + ref fp32 band 0.033 = 0.085 -> MARGIN_SC 0.15 (1.8x
// headroom). Flagged (DISJOINT): m3-m1<=M -> listB (full scan);
// else m2-m1<=M -> listA (2-cand exact fp64). Disjoint lists remove the
// 3a->3b ordering dep so one merged resolve kernel handles both.
// idx-only outputs; expand writes full 256B lines.
// R10 post-mortem: __launch_bounds__(256,6) squeezed arch VGPRs to 32 ->
// compiler parked za/tracking in AGPRs, v_accvgpr_read/write on every use
// inflated VALU ~3.5x (VALUBusy 45% at only 10% MfmaUtil). (256,4) caps
// at 128 -> live set (~70) fits in arch VGPRs, no shuffle churn.
#define MARGIN_SC 0.15f
#define BAND 1e-4f                  // full-scan fp32-prefilter band (unscaled)

typedef __attribute__((ext_vector_type(8)))  _Float16 f16x8;  // MFMA A/B frag
typedef __attribute__((ext_vector_type(4)))  float    f32x4;

// ---------------------------------------------------------------------------
// prep: blocks 0..3  -> Bsum[k] (numpy-pairwise, contract off) + 1024*Bsum
//       blocks 4..67 -> codebook*1024 as fp16 in 16x16x32 MFMA B-frag order
// frag layout: half off = ((c*4+s)*64 + l)*8 + j   (c=tile of 16 codes,
// s=kchunk of 32; lane l holds B[k=s*32+(l>>4)*8+j][n=c*16+(l&15)]).
// block 0 thread 0 also zeroes cntA/cntB (prep completes before phase1).
// ---------------------------------------------------------------------------
__global__ __launch_bounds__(256) void prep_kernel(const float* __restrict__ cb,
                                                   float* __restrict__ Bsum,
                                                   float* __restrict__ Bs1024,
                                                   _Float16* __restrict__ bs16,
                                                   int* __restrict__ cnts) {
    int bid = blockIdx.x;
    if (bid < 4) {
        if (bid == 0 && threadIdx.x == 0) { cnts[0] = 0; cnts[1] = 0; }
        {
#pragma clang fp contract(off)
            int k = bid * 256 + threadIdx.x;
            const float* row = cb + k * DDIM;
            float r0,r1,r2,r3,r4,r5,r6,r7;
            r0 = row[0]*row[0]; r1 = row[1]*row[1]; r2 = row[2]*row[2]; r3 = row[3]*row[3];
            r4 = row[4]*row[4]; r5 = row[5]*row[5]; r6 = row[6]*row[6]; r7 = row[7]*row[7];
#pragma unroll
            for (int i = 8; i < DDIM; i += 8) {
                r0 += row[i+0]*row[i+0]; r1 += row[i+1]*row[i+1];
                r2 += row[i+2]*row[i+2]; r3 += row[i+3]*row[i+3];
                r4 += row[i+4]*row[i+4]; r5 += row[i+5]*row[i+5];
                r6 += row[i+6]*row[i+6]; r7 += row[i+7]*row[i+7];
            }
            float bs = ((r0+r1)+(r2+r3)) + ((r4+r5)+(r6+r7));
            Bsum[k] = bs;
            Bs1024[k] = 1024.0f * bs;          // pow2 scale: exact
        }
    } else {
        int t = (bid - 4) * 256 + threadIdx.x; // 16384 = 64c * 4s * 64l
        int c = t >> 8, s = (t >> 6) & 3, l = t & 63;
        int n = l & 15, kg = l >> 4;
        int code = c * 16 + n;
        int d0 = s * 32 + kg * 8;
        const float* row = cb + code * DDIM + d0;
        f32x4 f0 = *(const f32x4*)(row);
        f32x4 f1 = *(const f32x4*)(row + 4);
        f16x8 v;
#pragma unroll
        for (int e = 0; e < 4; ++e) {
            v[e]     = (_Float16)(1024.0f * f0[e]);   // RNE cvt
            v[4 + e] = (_Float16)(1024.0f * f1[e]);
        }
        *(f16x8*)(bs16 + ((size_t)((c * 4 + s) * 64 + l)) * 8) = v;
    }
}

// ---------------------------------------------------------------------------
// phase1: fp16 16x16x32 MFMA distance (scaled by 1024) + top-3 argmin.
// Wave owns 16 px; 8192 waves, 4 independent waves/block, NO loop barriers,
// NO LDS staging: B fragments stream from L2/L1 (4 waves/block in loose
// lockstep -> L1 reuse). acc init = 1024*Bsum[k] (4KB, L1-resident).
// A: m=lane&15 -> w=w0+m, k=(lane>>4)*8+e (K=32/chunk, 4 chunks).
// C/D: col(code)=lane&15, row(pixel)=(lane>>4)*4+r.
// Tracks (m1,i1,m2,i2,m3); DISJOINT flags: m3-m1<=M -> listB else
// m2-m1<=M -> listA{pix,k1,k2}.
// ---------------------------------------------------------------------------
__global__ __launch_bounds__(256, 4) void phase1_mfma(
    const float* __restrict__ z, const _Float16* __restrict__ bs16,
    const float* __restrict__ Bs1024, int* __restrict__ idx,
    int* __restrict__ cntA, int2* __restrict__ listA,
    int* __restrict__ cntB, int* __restrict__ listB)
{
    __shared__ int idxb[64];
    const int tid = threadIdx.x;
    const int lane = tid & 63, wv = tid >> 6;
    const int gw = blockIdx.x * 4 + wv;        // 8192 waves, 16 px each
    const int b = gw >> 8;
    const int rem = gw & 255;
    const int h = rem >> 2;
    const int w0 = (rem & 3) * 16;
    const int col = lane & 15, kg = lane >> 4;

    // A fragments: pixel m=col -> w=w0+col; chunk s covers d=s*32+kg*8+e
    const float* zbase = z + (size_t)b * BSTRIDE + h * HW + w0 + col;
    f16x8 za[4];
#pragma unroll
    for (int s = 0; s < 4; ++s) {
        const float* zp = zbase + (size_t)(s * 32 + kg * 8) * PLANE;
        f16x8 a;
#pragma unroll
        for (int e = 0; e < 8; ++e)
            a[e] = (_Float16)(-2.0f * zp[(size_t)e * PLANE]);
        za[s] = a;
    }

    float m1[4], m2[4], m3[4]; int i1[4], i2[4];
#pragma unroll
    for (int r = 0; r < 4; ++r) {
        m1[r] = 3.4e38f; m2[r] = 3.4e38f; m3[r] = 3.4e38f; i1[r] = 0; i2[r] = 0;
    }

    const f16x8* bfrag = (const f16x8*)bs16;
    for (int c = 0; c < 64; ++c) {             // 16-code tiles
        int kcol = c * 16 + col;
        float bsv = Bs1024[kcol];              // 4KB table, L1-resident
        f32x4 acc = { bsv, bsv, bsv, bsv };
#pragma unroll
        for (int s = 0; s < 4; ++s) {
            f16x8 bh = bfrag[(c * 4 + s) * 64 + lane];   // coalesced dwordx4
            acc = __builtin_amdgcn_mfma_f32_16x16x32_f16(za[s], bh, acc, 0, 0, 0);
        }
        // sorted-3 insert: med3 for values, cndmask for indices
#pragma unroll
        for (int r = 0; r < 4; ++r) {
            float dv = acc[r];
            bool lt1 = dv < m1[r];
            bool lt2 = dv < m2[r];
            m3[r] = __builtin_amdgcn_fmed3f(m2[r], m3[r], dv);
            m2[r] = __builtin_amdgcn_fmed3f(m1[r], m2[r], dv);
            i2[r] = lt1 ? i1[r] : (lt2 ? kcol : i2[r]);
            i1[r] = lt1 ? kcol : i1[r];        // strict < keeps lowest index
            m1[r] = fminf(m1[r], dv);
        }
    }

    // merge sorted-3 tuples across the 16 lanes (code columns) per row group
#pragma unroll
    for (int mask = 1; mask <= 8; mask <<= 1) {
#pragma unroll
        for (int r = 0; r < 4; ++r) {
            float b1 = __shfl_xor(m1[r], mask, 64);
            float b2 = __shfl_xor(m2[r], mask, 64);
            float b3 = __shfl_xor(m3[r], mask, 64);
            int  ib1 = __shfl_xor(i1[r], mask, 64);
            int  ib2 = __shfl_xor(i2[r], mask, 64);
            float a1 = m1[r], a2 = m2[r], a3 = m3[r];
            int  ia1 = i1[r], ia2 = i2[r];
            bool bfi = (b1 < a1) || (b1 == a1 && ib1 < ia1);
            float x1 = bfi ? b1 : a1;  int xi1 = bfi ? ib1 : ia1;
            float x2 = bfi ? b2 : a2;  int xi2 = bfi ? ib2 : ia2;
            float x3 = bfi ? b3 : a3;
            float y1 = bfi ? a1 : b1;  int yi1 = bfi ? ia1 : ib1;
            float y2 = bfi ? a2 : b2;
            bool ys = (y1 < x2) || (y1 == x2 && yi1 < xi2);
            m1[r] = x1; i1[r] = xi1;
            m2[r] = ys ? y1 : x2;  i2[r] = ys ? yi1 : xi2;
            m3[r] = ys ? fminf(x2, y2) : fminf(x3, y1);
        }
    }

    if (col == 0) {                  // 4 writer lanes/wave; rows kg*4+r
#pragma unroll
        for (int r = 0; r < 4; ++r) {
            int row = kg * 4 + r;
            idxb[wv * 16 + row] = i1[r];
            if (m2[r] - m1[r] <= MARGIN_SC) {           // ambiguous
                int pix = gw * 16 + row;
                if (m3[r] - m1[r] <= MARGIN_SC) {       // >=3 cands: B only
                    int pb = atomicAdd(cntB, 1);
                    if (pb < CAP_B) listB[pb] = pix;
                } else {                                // exactly-2 cands
                    int pos = atomicAdd(cntA, 1);
                    if (pos < CAP_A) {
                        int2 rec; rec.x = pix; rec.y = i1[r] | (i2[r] << 16);
                        listA[pos] = rec;
                    }
                }
            }
        }
    }
    __syncthreads();                 // single end-of-kernel rendezvous

    if (tid < 64) idx[blockIdx.x * 64 + tid] = idxb[tid];  // coalesced dump
}

// ---------------------------------------------------------------------------
// resolve: merged exact resolver. Waves grid-stride over listA (2-cand fp64
// exact) then listB (full-scan exact); lists are DISJOINT so order-free.
// 2-cand: A = numpy-pairwise sum z^2 (fp32, contract off); p = fp64 dot
// (lane-split + shuffle reduce); D_k = fl32(fl32(A+Bsum_k)-fl32(2p));
// winner = lex min (D,k). Full scan: fp32 prefilter (16 codes/lane),
// candidates within smin+BAND -> fp64 exact, wave-reduce lex min.
// ---------------------------------------------------------------------------
__global__ __launch_bounds__(256, 2) void resolve_kernel(
    const float* __restrict__ z, const float* __restrict__ cb,
    const float* __restrict__ Bsum, int* __restrict__ idx,
    const int* __restrict__ cnts, const int2* __restrict__ listA,
    const int* __restrict__ listB)
{
    __shared__ float zsh[4][128];
    const int tid = threadIdx.x, lane = tid & 63, wv = tid >> 6;
    int gwave = (blockIdx.x * 256 + tid) >> 6;
    int nwaves = gridDim.x * 4;
    int nA = cnts[0]; if (nA > CAP_A) nA = CAP_A;
    int nB = cnts[1]; if (nB > CAP_B) nB = CAP_B;
    int ntot = nA + nB;

    for (int item = gwave; item < ntot; item += nwaves) {
        int pix, k1 = 0, k2 = 0;
        bool full = item >= nA;
        if (full) pix = listB[item - nA];
        else { int2 rec = listA[item]; pix = rec.x;
               k1 = rec.y & 0xFFFF; k2 = rec.y >> 16; }
        int b = pix >> 12, h = (pix >> 6) & 63, w = pix & 63;
        const float* zp = z + (size_t)b * BSTRIDE + h * HW + w;

        float za = zp[(size_t)lane * PLANE];
        float zb = zp[(size_t)(lane + 64) * PLANE];
        zsh[wv][lane] = za;                    // wave-internal: in-order LDS
        zsh[wv][lane + 64] = zb;
        const float* zr = zsh[wv];

        float Apair;
        {
#pragma clang fp contract(off)
            float r0,r1,r2,r3,r4,r5,r6,r7;
            r0 = zr[0]*zr[0]; r1 = zr[1]*zr[1]; r2 = zr[2]*zr[2]; r3 = zr[3]*zr[3];
            r4 = zr[4]*zr[4]; r5 = zr[5]*zr[5]; r6 = zr[6]*zr[6]; r7 = zr[7]*zr[7];
#pragma unroll
            for (int i = 8; i < DDIM; i += 8) {
                r0 += zr[i+0]*zr[i+0]; r1 += zr[i+1]*zr[i+1];
                r2 += zr[i+2]*zr[i+2]; r3 += zr[i+3]*zr[i+3];
                r4 += zr[i+4]*zr[i+4]; r5 += zr[i+5]*zr[i+5];
                r6 += zr[i+6]*zr[i+6]; r7 += zr[i+7]*zr[i+7];
            }
            Apair = ((r0+r1)+(r2+r3)) + ((r4+r5)+(r6+r7));
        }

        int wk;
        if (!full) {
            // -------- 2-candidate exact path --------
            const float* c1 = cb + (size_t)k1 * DDIM;
            const float* c2 = cb + (size_t)k2 * DDIM;
            double p1 = fma((double)za, (double)c1[lane],
                            (double)zb * (double)c1[lane + 64]);
            double p2 = fma((double)za, (double)c2[lane],
                            (double)zb * (double)c2[lane + 64]);
            for (int off = 32; off; off >>= 1) {
                p1 += __shfl_xor(p1, off, 64);
                p2 += __shfl_xor(p2, off, 64);
            }
            float u1 = (float)(2.0 * p1), u2 = (float)(2.0 * p2);
            float D1, D2;
            {
#pragma clang fp contract(off)
                float t1 = Apair + Bsum[k1];
                float t2 = Apair + Bsum[k2];
                D1 = t1 - u1; D2 = t2 - u2;
            }
            wk = (D1 < D2 || (D1 == D2 && k1 < k2)) ? k1 : k2;
        } else {
            // -------- full-scan exact path --------
            float dot[16];
#pragma unroll
            for (int g = 0; g < 16; ++g) dot[g] = 0.0f;
            for (int i = 0; i < 32; ++i) {
                f32x4 zv = *(const f32x4*)(zr + i * 4);   // broadcast LDS
#pragma unroll
                for (int g = 0; g < 16; ++g) {
                    const f32x4 cv = *(const f32x4*)(cb + (size_t)(g * 64 + lane) * DDIM + i * 4);
                    dot[g] = __builtin_fmaf(zv[0], cv[0],
                             __builtin_fmaf(zv[1], cv[1],
                             __builtin_fmaf(zv[2], cv[2],
                             __builtin_fmaf(zv[3], cv[3], dot[g]))));
                }
            }
            float est[16]; float smin = 3.4e38f;
#pragma unroll
            for (int g = 0; g < 16; ++g) {
                est[g] = Bsum[g * 64 + lane] - 2.0f * dot[g];
                smin = fminf(smin, est[g]);
            }
            for (int off = 32; off; off >>= 1)
                smin = fminf(smin, __shfl_xor(smin, off, 64));

            float bd = 3.4e38f; int bk = 1 << 30;
#pragma unroll
            for (int g = 0; g < 16; ++g) {
                if (est[g] <= smin + BAND) {
                    int k = g * 64 + lane;
                    const float* c = cb + (size_t)k * DDIM;
                    double p = 0.0;
                    for (int i = 0; i < DDIM; ++i)
                        p = fma((double)zr[i], (double)c[i], p);
                    float Dk;
                    {
#pragma clang fp contract(off)
                        float t1 = Apair + Bsum[k];
                        float u = (float)(2.0 * p);
                        Dk = t1 - u;
                    }
                    if (Dk < bd || (Dk == bd && k < bk)) { bd = Dk; bk = k; }
                }
            }
            for (int off = 32; off; off >>= 1) {
                float od = __shfl_xor(bd, off, 64);
                int   ok = __shfl_xor(bk, off, 64);
                bool better = (od < bd) || (od == bd && ok < bk);
                bd = better ? od : bd;
                bk = better ? ok : bk;
            }
            wk = bk;
        }
        if (lane == 0) idx[pix] = wk;
    }
}

// ---------------------------------------------------------------------------
// expand: out[b,:,h,w] = cb[idx[pix]]. Block = one (b,h) row; lane = w so
// every store instruction writes one full 256-B contiguous w-row (no RMW,
// no partial lines). cb gather per block touches <=32 KB -> L1-resident.
// ---------------------------------------------------------------------------
__global__ __launch_bounds__(256) void expand_kernel(
    const float* __restrict__ cb, const int* __restrict__ idx,
    float* __restrict__ out)
{
    const int blk = blockIdx.x;                // 2048 = b*64 + h
    const int b = blk >> 6, h = blk & 63;
    const int tid = threadIdx.x, w = tid & 63, wv = tid >> 6;
    const int id = idx[blk * 64 + w];          // same 64 ids per wave (L1)
    const float* crow = cb + (size_t)id * DDIM;
    float* ob = out + (size_t)b * BSTRIDE + h * HW + w;
#pragma unroll
    for (int d0 = 0; d0 < 32; d0 += 4) {
        int d = wv * 32 + d0;
        f32x4 v = *(const f32x4*)(crow + d);   // 16B gather per lane
        ob[(size_t)(d + 0) * PLANE] = v[0];
        ob[(size_t)(d + 1) * PLANE] = v[1];
        ob[(size_t)(d + 2) * PLANE] = v[2];
        ob[(size_t)(d + 3) * PLANE] = v[3];
    }
}

// ---------------------------------------------------------------------------
extern "C" void kernel_launch(void* const* d_in, const int* in_sizes, int n_in,
                              void* d_out, int out_size, void* d_ws, size_t ws_size,
                              hipStream_t stream) {
    const float* z  = (const float*)d_in[0];
    const float* cb = (const float*)d_in[1];
    float* out = (float*)d_out;

    // ws: Bsum 4K | Bs1024 4K | cnts 4K | bs16 256K | listA 512K | listB 32K
    //     | idx 512K
    float* Bsum   = (float*)d_ws;
    float* Bs1024 = (float*)((char*)d_ws + 4096);
    int*   cnts   = (int*)((char*)d_ws + 8192);
    _Float16* bs16 = (_Float16*)((char*)d_ws + 12288);
    int2*  listA  = (int2*)((char*)d_ws + 12288 + 262144);
    int*   listB  = (int*)((char*)d_ws + 12288 + 262144 + 524288);
    int*   idx    = (int*)((char*)d_ws + 12288 + 262144 + 524288 + 32768);

    prep_kernel<<<68, 256, 0, stream>>>(cb, Bsum, Bs1024, bs16, cnts);
    phase1_mfma<<<NPIX / 64, 256, 0, stream>>>(z, bs16, Bs1024, idx,
                                               cnts, listA, cnts + 1, listB);
    resolve_kernel<<<1024, 256, 0, stream>>>(z, cb, Bsum, idx, cnts,
                                             listA, listB);
    expand_kernel<<<2048, 256, 0, stream>>>(cb, idx, out);
}